// Round 18
// baseline (418.779 us; speedup 1.0000x reference)
//
#include <hip/hip_runtime.h>
#include <hip/hip_bf16.h>

#define HF 128
#define GG 128
#define CC 10
#define EPS 1e-5f
#define TSTR 129          // padded LDS transpose stride (floats, mgemm)
#define BSTR 136          // padded LDS transpose stride (ushorts, fillfeat)
#define CAP 2048          // per-block cached CSR entries (16 KB)

typedef __attribute__((ext_vector_type(8))) short short8;
typedef __attribute__((ext_vector_type(4))) float f32x4;

__device__ inline unsigned short f2bf(float f) {
    unsigned int u = __float_as_uint(f);
    return (unsigned short)((u + 0x7FFFu + ((u >> 16) & 1u)) >> 16);
}

__device__ inline float bf2f(unsigned short h) {
    return __uint_as_float(((unsigned int)h) << 16);
}

// acc[0..7] += w * sext_int8x8(x,y)   (signed int8, exact decode)
__device__ inline void i8acc(float* acc, unsigned int x, unsigned int y, float w) {
    acc[0] = fmaf(w, (float)((int)(x << 24) >> 24), acc[0]);
    acc[1] = fmaf(w, (float)((int)(x << 16) >> 24), acc[1]);
    acc[2] = fmaf(w, (float)((int)(x << 8) >> 24), acc[2]);
    acc[3] = fmaf(w, (float)((int)x >> 24), acc[3]);
    acc[4] = fmaf(w, (float)((int)(y << 24) >> 24), acc[4]);
    acc[5] = fmaf(w, (float)((int)(y << 16) >> 24), acc[5]);
    acc[6] = fmaf(w, (float)((int)(y << 8) >> 24), acc[6]);
    acc[7] = fmaf(w, (float)((int)y >> 24), acc[7]);
}

// acc[0..15] += w * sext_int8x16(u)
__device__ inline void i8acc16(float* acc, uint4 u, float w) {
    i8acc(acc, u.x, u.y, w);
    i8acc(acc + 8, u.z, u.w, w);
}

__device__ inline unsigned int pk4i8(float a, float b, float c, float d, float inv) {
    int q0 = (int)rintf(a * inv), q1 = (int)rintf(b * inv);
    int q2 = (int)rintf(c * inv), q3 = (int)rintf(d * inv);
    return (unsigned int)(q0 & 255) | ((unsigned int)(q1 & 255) << 8) |
           ((unsigned int)(q2 & 255) << 16) | ((unsigned int)(q3 & 255) << 24);
}

// ---------------- standalone degree count + rank capture (low footprint) ----------------
__global__ __launch_bounds__(256) void k_count(const int* __restrict__ ei, int E,
                                               int* cs, int* cd, int* __restrict__ rank) {
    int e = blockIdx.x * 256 + threadIdx.x;
    if (e < E) {
        atomicAdd(&cs[ei[e]], 1);
        rank[e] = atomicAdd(&cd[ei[E + e]], 1);
    }
}

// ---------------- BN stats over x (widened loads) ----------------
__global__ __launch_bounds__(256) void k_colstats(const float* __restrict__ X, float* stats,
                                                  int n) {
    int c4 = (threadIdx.x & 31) * 4;
    int rl = threadIdx.x >> 5;
    float s0 = 0.f, s1 = 0.f, s2 = 0.f, s3 = 0.f;
    float q0 = 0.f, q1 = 0.f, q2 = 0.f, q3 = 0.f;
    for (int i = blockIdx.x * 8 + rl; i < n; i += gridDim.x * 8) {
        float4 v = *(const float4*)(X + (size_t)i * HF + c4);
        s0 += v.x; q0 += v.x * v.x;
        s1 += v.y; q1 += v.y * v.y;
        s2 += v.z; q2 += v.z * v.z;
        s3 += v.w; q3 += v.w * v.w;
    }
    __shared__ float sh[2048];
    sh[rl * 128 + c4 + 0] = s0; sh[rl * 128 + c4 + 1] = s1;
    sh[rl * 128 + c4 + 2] = s2; sh[rl * 128 + c4 + 3] = s3;
    sh[1024 + rl * 128 + c4 + 0] = q0; sh[1024 + rl * 128 + c4 + 1] = q1;
    sh[1024 + rl * 128 + c4 + 2] = q2; sh[1024 + rl * 128 + c4 + 3] = q3;
    __syncthreads();
    if (threadIdx.x < 128) {
        float ts = 0.f, tq = 0.f;
        for (int g = 0; g < 8; g++) {
            ts += sh[g * 128 + threadIdx.x];
            tq += sh[1024 + g * 128 + threadIdx.x];
        }
        atomicAdd(&stats[threadIdx.x], ts);
        atomicAdd(&stats[HF + threadIdx.x], tq);
    }
}

// ------- BN fold -------
__global__ void k_foldbias(const float* __restrict__ stats, float cntInv,
                           const float* __restrict__ g, const float* __restrict__ b,
                           const float* __restrict__ W, unsigned short* __restrict__ Wtb,
                           float* __restrict__ biasT) {
    int n = blockIdx.x, k = threadIdx.x;
    float mean = stats[k] * cntInv;
    float var = stats[HF + k] * cntInv - mean * mean;
    float sc = g[k] * rsqrtf(var + EPS);
    float shf = b[k] - mean * sc;
    float wkn = W[k * HF + n];
    Wtb[n * HF + k] = f2bf(sc * wkn);
    __shared__ float red[128];
    red[k] = shf * wkn;
    __syncthreads();
    for (int o = 64; o > 0; o >>= 1) {
        if (k < o) red[k] += red[k + o];
        __syncthreads();
    }
    if (k == 0) biasT[n] = red[0];
}

__global__ void k_scan1(const int* __restrict__ cd, const int* __restrict__ cs,
                        float* __restrict__ dis, int* offs, int* bsum, int n) {
    __shared__ int sh[256];
    int t = threadIdx.x, i = blockIdx.x * 256 + t;
    if (i < n) dis[i] = rsqrtf((float)(1 + cs[i]));
    int v = (i < n) ? cd[i] : 0;
    sh[t] = v; __syncthreads();
    for (int o = 1; o < 256; o <<= 1) {
        int x = (t >= o) ? sh[t - o] : 0;
        __syncthreads();
        sh[t] += x;
        __syncthreads();
    }
    if (i < n) offs[i] = sh[t] - v;
    if (t == 255) bsum[blockIdx.x] = sh[255];
}

__global__ void k_scan2(const int* __restrict__ bsum, int* bscan, int nb) {
    __shared__ int sh[256];
    int t = threadIdx.x;
    int v = (t < nb) ? bsum[t] : 0;
    sh[t] = v; __syncthreads();
    for (int o = 1; o < 256; o <<= 1) {
        int x = (t >= o) ? sh[t - o] : 0;
        __syncthreads();
        sh[t] += x;
        __syncthreads();
    }
    if (t < nb) bscan[t] = sh[t] - v;
}

__global__ void k_scan3(int* offs, const int* __restrict__ bscan, int n) {
    int i = blockIdx.x * 256 + threadIdx.x;
    if (i < n) offs[i] += bscan[blockIdx.x];
}

// ---- fused: feat-layer MFMA GEMM (blocks [0,gB)) + CSR fill (rest) ----
// Both depend only on {foldbias-feat, scan3}; fill is fire-and-forget scattered stores,
// tolerant of the GEMM's register footprint (unlike atomics-with-return).
__global__ __launch_bounds__(256) void k_fillfeat(const float* __restrict__ Ain,
                                                  const unsigned short* __restrict__ Wtb,
                                                  const float* __restrict__ biasT,
                                                  unsigned short* __restrict__ outv,
                                                  float* __restrict__ stats, int n, int gB,
                                                  const int* __restrict__ ei, int E,
                                                  const float* __restrict__ dis,
                                                  const int* __restrict__ offs,
                                                  const int* __restrict__ rank,
                                                  int2* __restrict__ epk) {
    __shared__ unsigned short Lsb[4][16 * BSTR];   // 17.4 KB
    __shared__ float bsh[128];
    if ((int)blockIdx.x >= gB) {
        int e = ((int)blockIdx.x - gB) * 256 + threadIdx.x;
        if (e < E) {
            int s = ei[e], d = ei[E + e];
            epk[offs[d] + rank[e]] = make_int2(s, __float_as_int(dis[s] * dis[d]));
        }
        return;
    }
    int l = threadIdx.x & 63, w = threadIdx.x >> 6;
    int lr = l & 15, lc = l >> 4;
    int rowbase = (int)blockIdx.x * 128 + w * 32;
    if (threadIdx.x < 128) bsh[threadIdx.x] = biasT[threadIdx.x];

    f32x4 acc[2][8];
#pragma unroll
    for (int rt = 0; rt < 2; rt++)
#pragma unroll
        for (int nt = 0; nt < 8; nt++) acc[rt][nt] = (f32x4){0.f, 0.f, 0.f, 0.f};

    union U { uint4 u; short8 s; };

    for (int ks = 0; ks < 4; ks++) {
        short8 af[2];
#pragma unroll
        for (int rt = 0; rt < 2; rt++) {
            int row = rowbase + rt * 16 + lr;
            if (row < n) {
                const float4* xp = (const float4*)(Ain + (size_t)row * HF + ks * 32 + lc * 8);
                float4 v0 = xp[0], v1 = xp[1];
                short8 a;
                a[0] = (short)f2bf(v0.x); a[1] = (short)f2bf(v0.y);
                a[2] = (short)f2bf(v0.z); a[3] = (short)f2bf(v0.w);
                a[4] = (short)f2bf(v1.x); a[5] = (short)f2bf(v1.y);
                a[6] = (short)f2bf(v1.z); a[7] = (short)f2bf(v1.w);
                af[rt] = a;
            } else af[rt] = (short8){0,0,0,0,0,0,0,0};
        }
#pragma unroll
        for (int nt = 0; nt < 8; nt++) {
            U ub;
            ub.u = *(const uint4*)(Wtb + (size_t)(nt * 16 + lr) * HF + ks * 32 + lc * 8);
            acc[0][nt] = __builtin_amdgcn_mfma_f32_16x16x32_bf16(af[0], ub.s, acc[0][nt], 0, 0, 0);
            acc[1][nt] = __builtin_amdgcn_mfma_f32_16x16x32_bf16(af[1], ub.s, acc[1][nt], 0, 0, 0);
        }
    }
    __syncthreads();   // bsh ready

    // bias+relu in-register -> stats + bf16 LDS tile -> coalesced copy-out
    float s[8], q[8];
#pragma unroll
    for (int nt = 0; nt < 8; nt++) { s[nt] = 0.f; q[nt] = 0.f; }
    unsigned short* LsW = Lsb[w];
    for (int rt = 0; rt < 2; rt++) {
#pragma unroll
        for (int nt = 0; nt < 8; nt++) {
            float bias = bsh[nt * 16 + lr];
#pragma unroll
            for (int r = 0; r < 4; r++) {
                int row = rowbase + rt * 16 + lc * 4 + r;
                float vf = 0.f;
                if (row < n) {
                    vf = fmaxf(acc[rt][nt][r] + bias, 0.f);
                    s[nt] += vf; q[nt] += vf * vf;
                }
                LsW[(lc * 4 + r) * BSTR + nt * 16 + lr] = f2bf(vf);
            }
        }
        __syncthreads();
        int r16 = l >> 2, cc = (l & 3) * 32;
        int row = rowbase + rt * 16 + r16;
        if (row < n) {
            const uint4* src = (const uint4*)(LsW + r16 * BSTR + cc);
            uint4* dst = (uint4*)(outv + (size_t)row * HF + cc);
            dst[0] = src[0]; dst[1] = src[1]; dst[2] = src[2]; dst[3] = src[3];
        }
        __syncthreads();
    }

#pragma unroll
    for (int nt = 0; nt < 8; nt++) {
        s[nt] += __shfl_xor(s[nt], 16);
        q[nt] += __shfl_xor(q[nt], 16);
        s[nt] += __shfl_xor(s[nt], 32);
        q[nt] += __shfl_xor(q[nt], 32);
    }
    if (lc == 0) {
#pragma unroll
        for (int nt = 0; nt < 8; nt++) {
            atomicAdd(&stats[nt * 16 + lr], s[nt]);
            atomicAdd(&stats[HF + nt * 16 + lr], q[nt]);
        }
    }
}

// ---------------- MFMA GEMM (conv layers) ----------------
template <int RELU, int STATS, int OUTQ>
__global__ __launch_bounds__(256) void k_mgemm(const unsigned short* __restrict__ Ain,
                                               const unsigned short* __restrict__ Wtb,
                                               const float* __restrict__ biasT,
                                               void* __restrict__ outv,
                                               float* __restrict__ rowscl,
                                               int n, float* stats) {
    __shared__ float Ls[4][16 * TSTR];
    __shared__ float bsh[128];
    int l = threadIdx.x & 63, w = threadIdx.x >> 6;
    int lr = l & 15, lc = l >> 4;
    int rowbase = blockIdx.x * 128 + w * 32;
    if (threadIdx.x < 128) bsh[threadIdx.x] = biasT[threadIdx.x];

    f32x4 acc[2][8];
#pragma unroll
    for (int rt = 0; rt < 2; rt++)
#pragma unroll
        for (int nt = 0; nt < 8; nt++) acc[rt][nt] = (f32x4){0.f, 0.f, 0.f, 0.f};

    union U { uint4 u; short8 s; };

    for (int ks = 0; ks < 4; ks++) {
        short8 af[2];
#pragma unroll
        for (int rt = 0; rt < 2; rt++) {
            int row = rowbase + rt * 16 + lr;
            if (row < n) {
                U u;
                u.u = *(const uint4*)(Ain + (size_t)row * HF + ks * 32 + lc * 8);
                af[rt] = u.s;
            } else af[rt] = (short8){0,0,0,0,0,0,0,0};
        }
#pragma unroll
        for (int nt = 0; nt < 8; nt++) {
            U ub;
            ub.u = *(const uint4*)(Wtb + (size_t)(nt * 16 + lr) * HF + ks * 32 + lc * 8);
            acc[0][nt] = __builtin_amdgcn_mfma_f32_16x16x32_bf16(af[0], ub.s, acc[0][nt], 0, 0, 0);
            acc[1][nt] = __builtin_amdgcn_mfma_f32_16x16x32_bf16(af[1], ub.s, acc[1][nt], 0, 0, 0);
        }
    }
    __syncthreads();

    if (STATS) {
        float s[8], q[8];
#pragma unroll
        for (int nt = 0; nt < 8; nt++) { s[nt] = 0.f; q[nt] = 0.f; }
#pragma unroll
        for (int rt = 0; rt < 2; rt++) {
#pragma unroll
            for (int nt = 0; nt < 8; nt++) {
                float bias = bsh[nt * 16 + lr];
#pragma unroll
                for (int r = 0; r < 4; r++) {
                    int row = rowbase + rt * 16 + lc * 4 + r;
                    if (row < n) {
                        float v = acc[rt][nt][r] + bias;
                        if (RELU) v = fmaxf(v, 0.f);
                        s[nt] += v; q[nt] += v * v;
                    }
                }
            }
        }
#pragma unroll
        for (int nt = 0; nt < 8; nt++) {
            s[nt] += __shfl_xor(s[nt], 16);
            q[nt] += __shfl_xor(q[nt], 16);
            s[nt] += __shfl_xor(s[nt], 32);
            q[nt] += __shfl_xor(q[nt], 32);
        }
        if (lc == 0) {
#pragma unroll
            for (int nt = 0; nt < 8; nt++) {
                atomicAdd(&stats[nt * 16 + lr], s[nt]);
                atomicAdd(&stats[HF + nt * 16 + lr], q[nt]);
            }
        }
    }

    float* LsW = Ls[w];
    for (int rt = 0; rt < 2; rt++) {
#pragma unroll
        for (int nt = 0; nt < 8; nt++)
#pragma unroll
            for (int r = 0; r < 4; r++)
                LsW[(lc * 4 + r) * TSTR + nt * 16 + lr] = acc[rt][nt][r];
        __syncthreads();
        int r16 = l >> 2, cc = (l & 3) * 32;
        int row = rowbase + rt * 16 + r16;
        if (row < n) {
            float v[32];
#pragma unroll
            for (int j = 0; j < 32; j++) {
                float tv = LsW[r16 * TSTR + cc + j] + bsh[cc + j];
                if (RELU) tv = fmaxf(tv, 0.f);
                v[j] = tv;
            }
            if (OUTQ) {
                float m = 0.f;
#pragma unroll
                for (int j = 0; j < 32; j++) m = fmaxf(m, fabsf(v[j]));
                m = fmaxf(m, __shfl_xor(m, 1));
                m = fmaxf(m, __shfl_xor(m, 2));
                float inv = (m > 1e-20f) ? 127.f / m : 0.f;
                unsigned int o[8];
#pragma unroll
                for (int j = 0; j < 8; j++)
                    o[j] = pk4i8(v[4 * j], v[4 * j + 1], v[4 * j + 2], v[4 * j + 3], inv);
                uint4* dst = (uint4*)((unsigned char*)outv + (size_t)row * 128 + cc);
                dst[0] = make_uint4(o[0], o[1], o[2], o[3]);
                dst[1] = make_uint4(o[4], o[5], o[6], o[7]);
                if ((l & 3) == 0) rowscl[row] = m * (1.f / 127.f);
            } else {
                unsigned int o[16];
#pragma unroll
                for (int j = 0; j < 16; j++)
                    o[j] = (unsigned int)f2bf(v[2 * j]) | ((unsigned int)f2bf(v[2 * j + 1]) << 16);
                uint4* dst = (uint4*)((unsigned short*)outv + (size_t)row * HF + cc);
                dst[0] = make_uint4(o[0], o[1], o[2], o[3]);
                dst[1] = make_uint4(o[4], o[5], o[6], o[7]);
                dst[2] = make_uint4(o[8], o[9], o[10], o[11]);
                dst[3] = make_uint4(o[12], o[13], o[14], o[15]);
            }
        }
        __syncthreads();
    }
}

// ------- aggregation: LDS-staged CSR (premultiplied weights) + signed int8 decode -------
template <int STATS>
__global__ __launch_bounds__(256) void k_agg(const unsigned char* __restrict__ B,
                                             const float* __restrict__ rsc,
                                             const int2* __restrict__ epk,
                                             const int* __restrict__ offs,
                                             const int* __restrict__ cnt,
                                             const float* __restrict__ dis,
                                             const float* __restrict__ convb,
                                             unsigned short* __restrict__ out,
                                             float* stats, int n) {
    __shared__ int2 cache[CAP];   // 16 KB; reused as float[4096] for stats
    int t = threadIdx.x;
    int lg = t & 7;
    int nb0 = blockIdx.x * 32;
    int node = nb0 + (t >> 3);
    int endNode = min(nb0 + 32, n);
    int segBase = (nb0 < n) ? offs[nb0] : 0;
    int segEnd = (endNode > nb0) ? (offs[endNode - 1] + cnt[endNode - 1]) : segBase;

    for (int idx = segBase + t; idx < segEnd; idx += 256) {
        int li = idx - segBase;
        if (li >= CAP) break;
        int2 p = epk[idx];
        cache[li] = make_int2(p.x, __float_as_int(__int_as_float(p.y) * rsc[p.x]));
    }
    __syncthreads();

    const uint4* Bv = (const uint4*)B;
    float acc[16];
#pragma unroll
    for (int k = 0; k < 16; k++) acc[k] = 0.f;
    float v[16];
    if (node < n) {
        float d = dis[node];
        i8acc16(acc, Bv[(size_t)node * 8 + lg], d * d * rsc[node]);
        int j0 = offs[node], e0 = j0 + cnt[node];
        if (e0 - segBase <= CAP) {
            int li = j0 - segBase, le = e0 - segBase;
            int2 p[8];
#pragma unroll
            for (int u = 0; u < 8; u++) p[u] = (li + u < le) ? cache[li + u] : make_int2(node, 0);
            while (li < le) {
                uint4 g0 = Bv[(size_t)p[0].x * 8 + lg];
                uint4 g1 = Bv[(size_t)p[1].x * 8 + lg];
                uint4 g2 = Bv[(size_t)p[2].x * 8 + lg];
                uint4 g3 = Bv[(size_t)p[3].x * 8 + lg];
                uint4 g4 = Bv[(size_t)p[4].x * 8 + lg];
                uint4 g5 = Bv[(size_t)p[5].x * 8 + lg];
                uint4 g6 = Bv[(size_t)p[6].x * 8 + lg];
                uint4 g7 = Bv[(size_t)p[7].x * 8 + lg];
                int ln = li + 8;
                int2 pn[8];
#pragma unroll
                for (int u = 0; u < 8; u++) pn[u] = (ln + u < le) ? cache[ln + u] : make_int2(node, 0);
                i8acc16(acc, g0, __int_as_float(p[0].y));
                i8acc16(acc, g1, __int_as_float(p[1].y));
                i8acc16(acc, g2, __int_as_float(p[2].y));
                i8acc16(acc, g3, __int_as_float(p[3].y));
                i8acc16(acc, g4, __int_as_float(p[4].y));
                i8acc16(acc, g5, __int_as_float(p[5].y));
                i8acc16(acc, g6, __int_as_float(p[6].y));
                i8acc16(acc, g7, __int_as_float(p[7].y));
#pragma unroll
                for (int u = 0; u < 8; u++) p[u] = pn[u];
                li = ln;
            }
        } else {
            for (int j = j0; j < e0; j++) {
                int2 p = epk[j];
                float wq = __int_as_float(p.y) * rsc[p.x];
                i8acc16(acc, Bv[(size_t)p.x * 8 + lg], wq);
            }
        }
        const float4* cb = (const float4*)convb;
        float4 b0 = cb[lg * 4], b1 = cb[lg * 4 + 1], b2 = cb[lg * 4 + 2], b3 = cb[lg * 4 + 3];
        v[0]  = fmaxf(acc[0]  + b0.x, 0.f); v[1]  = fmaxf(acc[1]  + b0.y, 0.f);
        v[2]  = fmaxf(acc[2]  + b0.z, 0.f); v[3]  = fmaxf(acc[3]  + b0.w, 0.f);
        v[4]  = fmaxf(acc[4]  + b1.x, 0.f); v[5]  = fmaxf(acc[5]  + b1.y, 0.f);
        v[6]  = fmaxf(acc[6]  + b1.z, 0.f); v[7]  = fmaxf(acc[7]  + b1.w, 0.f);
        v[8]  = fmaxf(acc[8]  + b2.x, 0.f); v[9]  = fmaxf(acc[9]  + b2.y, 0.f);
        v[10] = fmaxf(acc[10] + b2.z, 0.f); v[11] = fmaxf(acc[11] + b2.w, 0.f);
        v[12] = fmaxf(acc[12] + b3.x, 0.f); v[13] = fmaxf(acc[13] + b3.y, 0.f);
        v[14] = fmaxf(acc[14] + b3.z, 0.f); v[15] = fmaxf(acc[15] + b3.w, 0.f);
        uint4 o0, o1;
        o0.x = (unsigned int)f2bf(v[0])  | ((unsigned int)f2bf(v[1])  << 16);
        o0.y = (unsigned int)f2bf(v[2])  | ((unsigned int)f2bf(v[3])  << 16);
        o0.z = (unsigned int)f2bf(v[4])  | ((unsigned int)f2bf(v[5])  << 16);
        o0.w = (unsigned int)f2bf(v[6])  | ((unsigned int)f2bf(v[7])  << 16);
        o1.x = (unsigned int)f2bf(v[8])  | ((unsigned int)f2bf(v[9])  << 16);
        o1.y = (unsigned int)f2bf(v[10]) | ((unsigned int)f2bf(v[11]) << 16);
        o1.z = (unsigned int)f2bf(v[12]) | ((unsigned int)f2bf(v[13]) << 16);
        o1.w = (unsigned int)f2bf(v[14]) | ((unsigned int)f2bf(v[15]) << 16);
        uint4* op = (uint4*)out + (size_t)node * 16 + lg * 2;
        op[0] = o0; op[1] = o1;
    } else {
#pragma unroll
        for (int k = 0; k < 16; k++) v[k] = 0.f;
    }
    if (STATS) {
        __syncthreads();
        float* sh = (float*)cache;
        int nb = t >> 3;
#pragma unroll
        for (int k = 0; k < 16; k++) sh[nb * 128 + lg * 16 + k] = v[k];
        __syncthreads();
        if (t < 128) {
            float ts = 0.f, tq = 0.f;
            for (int g = 0; g < 32; g++) {
                float val = sh[g * 128 + t];
                ts += val; tq += val * val;
            }
            atomicAdd(&stats[t], ts);
            atomicAdd(&stats[HF + t], tq);
        }
    }
}

// ---------------- global add pool ----------------
__global__ __launch_bounds__(256) void k_pool(const unsigned short* __restrict__ A,
                                              const int* __restrict__ batch,
                                              float* gpool, int n) {
    int g = blockIdx.x >> 2, part = blockIdx.x & 3;
    int lo, hi;
    {
        int l = 0, r = n;
        while (l < r) { int m = (l + r) >> 1; if (batch[m] < g) l = m + 1; else r = m; }
        lo = l;
    }
    {
        int l = lo, r = n;
        while (l < r) { int m = (l + r) >> 1; if (batch[m] < g + 1) l = m + 1; else r = m; }
        hi = l;
    }
    int cntg = hi - lo;
    if (cntg <= 0) return;
    int per = (cntg + 3) >> 2;
    int s = lo + part * per, e = min(s + per, hi);
    int c2 = threadIdx.x & 63;
    int rl = threadIdx.x >> 6;
    float a0 = 0.f, a1 = 0.f;
    for (int i = s + rl; i < e; i += 4) {
        unsigned int u = ((const unsigned int*)(A + (size_t)i * HF))[c2];
        a0 += bf2f((unsigned short)(u & 0xFFFFu));
        a1 += bf2f((unsigned short)(u >> 16));
    }
    __shared__ float sh[512];
    sh[rl * 128 + c2 * 2] = a0;
    sh[rl * 128 + c2 * 2 + 1] = a1;
    __syncthreads();
    if (threadIdx.x < 128 && s < hi) {
        float s4 = sh[threadIdx.x] + sh[128 + threadIdx.x] + sh[256 + threadIdx.x] + sh[384 + threadIdx.x];
        atomicAdd(&gpool[g * HF + threadIdx.x], s4);
    }
}

// ---------------- head ----------------
__global__ void k_bnsmall(const float* __restrict__ in, const float* __restrict__ g,
                          const float* __restrict__ b, float* out) {
    int c = threadIdx.x;
    float s = 0.f, q = 0.f;
    for (int r = 0; r < GG; r++) { float v = in[r * HF + c]; s += v; q += v * v; }
    float mean = s / GG;
    float var = q / GG - mean * mean;
    float sc = g[c] * rsqrtf(var + EPS), sh = b[c] - mean * sc;
    for (int r = 0; r < GG; r++) out[r * HF + c] = in[r * HF + c] * sc + sh;
}

__global__ void k_fc(const float* __restrict__ Gbn, const float* __restrict__ Wfc,
                     const float* __restrict__ bfc, float* __restrict__ G2) {
    __shared__ float row[HF];
    int c = threadIdx.x, r = blockIdx.x;
    row[c] = Gbn[r * HF + c];
    __syncthreads();
    float acc = bfc[c];
    for (int k = 0; k < HF; k++) acc += row[k] * Wfc[k * HF + c];
    G2[r * HF + c] = fmaxf(acc, 0.f);
}

__global__ void k_head2(const float* __restrict__ G2, const float* __restrict__ g,
                        const float* __restrict__ b, const float* __restrict__ Wcls,
                        const float* __restrict__ bcls, float* __restrict__ scratch,
                        float* __restrict__ outp) {
    __shared__ float Ls[GG * HF];
    int c = threadIdx.x;
    float s = 0.f, q = 0.f;
    for (int r = 0; r < GG; r++) { float v = G2[r * HF + c]; s += v; q += v * v; }
    float mean = s / GG;
    float var = q / GG - mean * mean;
    float sc = g[c] * rsqrtf(var + EPS), sh = b[c] - mean * sc;
    for (int r = 0; r < GG; r++) Ls[r * HF + c] = G2[r * HF + c] * sc + sh;
    __syncthreads();
    for (int o = c; o < GG * CC; o += HF) {
        int r = o / CC, j = o % CC;
        float acc = bcls[j];
        for (int k = 0; k < HF; k++) acc += Ls[r * HF + k] * Wcls[k * CC + j];
        scratch[o] = acc;
    }
    __threadfence_block();
    __syncthreads();
    int r = c;
    float m = -1e30f;
    for (int j = 0; j < CC; j++) m = fmaxf(m, scratch[r * CC + j]);
    float se = 0.f;
    for (int j = 0; j < CC; j++) se += expf(scratch[r * CC + j] - m);
    float ls = logf(se);
    for (int j = 0; j < CC; j++) outp[r * CC + j] = scratch[r * CC + j] - m - ls;
}

extern "C" void kernel_launch(void* const* d_in, const int* in_sizes, int n_in,
                              void* d_out, int out_size, void* d_ws, size_t ws_size,
                              hipStream_t stream) {
    const float* x         = (const float*)d_in[0];
    const int*   ei        = (const int*)d_in[1];
    const int*   batch     = (const int*)d_in[2];
    const float* bn_feat_g = (const float*)d_in[3];
    const float* bn_feat_b = (const float*)d_in[4];
    const float* W_feat    = (const float*)d_in[5];
    const float* conv_bn_g = (const float*)d_in[6];
    const float* conv_bn_b = (const float*)d_in[7];
    const float* conv_W    = (const float*)d_in[8];
    const float* conv_b    = (const float*)d_in[9];
    const float* bn_fc_g   = (const float*)d_in[10];
    const float* bn_fc_b   = (const float*)d_in[11];
    const float* W_fc      = (const float*)d_in[12];
    const float* b_fc      = (const float*)d_in[13];
    const float* bn_hid_g  = (const float*)d_in[14];
    const float* bn_hid_b  = (const float*)d_in[15];
    const float* W_cls     = (const float*)d_in[16];
    const float* b_cls     = (const float*)d_in[17];
    float* outp = (float*)d_out;

    int N = in_sizes[0] / HF;
    int E = in_sizes[1] / 2;

    char* w = (char*)d_ws;
    size_t off = 0;
    auto al = [&](size_t bytes) -> void* {
        off = (off + 255) & ~(size_t)255;
        void* p = w + off;
        off += bytes;
        return p;
    };
    unsigned short* A  = (unsigned short*)al((size_t)N * HF * 2);   // bf16 node features
    unsigned char*  Bf = (unsigned char*)al((size_t)N * HF);        // int8 gather table
    float* rowscl = (float*)al((size_t)N * 4);
    int2*  epk    = (int2*)al((size_t)E * 8);
    int*   rank   = (int*)al((size_t)E * 4);
    float* dis    = (float*)al((size_t)N * 4);
    int*   offsb  = (int*)al((size_t)N * 4);
    unsigned short* Wtb = (unsigned short*)al(HF * HF * 2);
    float* biasT  = (float*)al(HF * 4);
    int*   bsum   = (int*)al(1024);
    int*   bscan  = (int*)al(1024);
    float* Gbn    = (float*)al(GG * HF * 4);
    float* G2     = (float*)al(GG * HF * 4);
    // zeroed region
    size_t z0 = (off + 255) & ~(size_t)255;
    off = z0;
    int*   cs    = (int*)al((size_t)N * 4);
    int*   cd    = (int*)al((size_t)N * 4);
    float* Sx    = (float*)al(2 * HF * 4);
    float* S0    = (float*)al(2 * HF * 4);
    float* S1    = (float*)al(2 * HF * 4);
    float* S2    = (float*)al(2 * HF * 4);
    float* gpool = (float*)al(GG * HF * 4);
    size_t zbytes = off - z0;
    hipMemsetAsync(w + z0, 0, zbytes, stream);

    int nbE = (E + 255) / 256;
    int nbN = (N + 255) / 256;
    int gemmGrid = (N + 127) / 128;

    // BN(x) stats, feat fold, degree count (standalone, high occupancy)
    k_colstats<<<400, 256, 0, stream>>>(x, Sx, N);
    k_foldbias<<<HF, HF, 0, stream>>>(Sx, 1.0f / N, bn_feat_g, bn_feat_b, W_feat, Wtb, biasT);
    k_count<<<nbE, 256, 0, stream>>>(ei, E, cs, cd, rank);

    // CSR offsets
    k_scan1<<<nbN, 256, 0, stream>>>(cd, cs, dis, offsb, bsum, N);
    k_scan2<<<1, 256, 0, stream>>>(bsum, bscan, nbN);
    k_scan3<<<nbN, 256, 0, stream>>>(offsb, bscan, N);

    // fused: feat GEMM (blocks [0,gemmGrid)) + CSR fill (rest) — independent work
    k_fillfeat<<<gemmGrid + nbE, 256, 0, stream>>>(x, Wtb, biasT, A, S0, N, gemmGrid,
                                                   ei, E, dis, offsb, rank, epk);

    float* Sarr[3] = {S0, S1, S2};
    for (int i = 0; i < 3; i++) {
        k_foldbias<<<HF, HF, 0, stream>>>(Sarr[i], 1.0f / N, conv_bn_g + i * HF, conv_bn_b + i * HF,
                                          conv_W + (size_t)i * HF * HF, Wtb, biasT);
        k_mgemm<0, 0, 1><<<gemmGrid, 256, 0, stream>>>(A, Wtb, biasT, Bf, rowscl, N, nullptr);
        if (i < 2)
            k_agg<1><<<(N + 31) / 32, 256, 0, stream>>>(Bf, rowscl, epk, offsb, cd, dis,
                                                        conv_b + i * HF, A, Sarr[i + 1], N);
        else
            k_agg<0><<<(N + 31) / 32, 256, 0, stream>>>(Bf, rowscl, epk, offsb, cd, dis,
                                                        conv_b + i * HF, A, nullptr, N);
    }

    // pool + head
    k_pool<<<GG * 4, 256, 0, stream>>>(A, batch, gpool, N);
    k_bnsmall<<<1, HF, 0, stream>>>(gpool, bn_fc_g, bn_fc_b, Gbn);
    k_fc<<<GG, HF, 0, stream>>>(Gbn, W_fc, b_fc, G2);
    k_head2<<<1, HF, 0, stream>>>(G2, bn_hid_g, bn_hid_b, W_cls, b_cls, Gbn, outp);
}

// Round 19
// 410.075 us; speedup vs baseline: 1.0212x; 1.0212x over previous
//
#include <hip/hip_runtime.h>
#include <hip/hip_bf16.h>

#define HF 128
#define GG 128
#define CC 10
#define EPS 1e-5f
#define TSTR 129          // padded LDS transpose stride (floats)
#define CAP 2048          // per-block cached CSR entries (16 KB)

typedef __attribute__((ext_vector_type(8))) short short8;
typedef __attribute__((ext_vector_type(4))) float f32x4;

__device__ inline unsigned short f2bf(float f) {
    unsigned int u = __float_as_uint(f);
    return (unsigned short)((u + 0x7FFFu + ((u >> 16) & 1u)) >> 16);
}

__device__ inline float bf2f(unsigned short h) {
    return __uint_as_float(((unsigned int)h) << 16);
}

// acc[0..7] += w * sext_int8x8(x,y)
__device__ inline void i8acc(float* acc, unsigned int x, unsigned int y, float w) {
    acc[0] = fmaf(w, (float)((int)(x << 24) >> 24), acc[0]);
    acc[1] = fmaf(w, (float)((int)(x << 16) >> 24), acc[1]);
    acc[2] = fmaf(w, (float)((int)(x << 8) >> 24), acc[2]);
    acc[3] = fmaf(w, (float)((int)x >> 24), acc[3]);
    acc[4] = fmaf(w, (float)((int)(y << 24) >> 24), acc[4]);
    acc[5] = fmaf(w, (float)((int)(y << 16) >> 24), acc[5]);
    acc[6] = fmaf(w, (float)((int)(y << 8) >> 24), acc[6]);
    acc[7] = fmaf(w, (float)((int)y >> 24), acc[7]);
}

__device__ inline void i8acc16(float* acc, uint4 u, float w) {
    i8acc(acc, u.x, u.y, w);
    i8acc(acc + 8, u.z, u.w, w);
}

__device__ inline unsigned int pk4i8(float a, float b, float c, float d, float inv) {
    int q0 = (int)rintf(a * inv), q1 = (int)rintf(b * inv);
    int q2 = (int)rintf(c * inv), q3 = (int)rintf(d * inv);
    return (unsigned int)(q0 & 255) | ((unsigned int)(q1 & 255) << 8) |
           ((unsigned int)(q2 & 255) << 16) | ((unsigned int)(q3 & 255) << 24);
}

// ---------------- standalone degree count + rank capture (low footprint) ----------------
__global__ __launch_bounds__(256) void k_count(const int* __restrict__ ei, int E,
                                               int* cs, int* cd, int* __restrict__ rank) {
    int e = blockIdx.x * 256 + threadIdx.x;
    if (e < E) {
        atomicAdd(&cs[ei[e]], 1);
        rank[e] = atomicAdd(&cd[ei[E + e]], 1);
    }
}

// ---------------- BN stats over x ----------------
__global__ __launch_bounds__(256) void k_colstats(const float* __restrict__ X, float* stats,
                                                  int n) {
    int c4 = (threadIdx.x & 31) * 4;
    int rl = threadIdx.x >> 5;
    float s0 = 0.f, s1 = 0.f, s2 = 0.f, s3 = 0.f;
    float q0 = 0.f, q1 = 0.f, q2 = 0.f, q3 = 0.f;
    for (int i = blockIdx.x * 8 + rl; i < n; i += gridDim.x * 8) {
        float4 v = *(const float4*)(X + (size_t)i * HF + c4);
        s0 += v.x; q0 += v.x * v.x;
        s1 += v.y; q1 += v.y * v.y;
        s2 += v.z; q2 += v.z * v.z;
        s3 += v.w; q3 += v.w * v.w;
    }
    __shared__ float sh[2048];
    sh[rl * 128 + c4 + 0] = s0; sh[rl * 128 + c4 + 1] = s1;
    sh[rl * 128 + c4 + 2] = s2; sh[rl * 128 + c4 + 3] = s3;
    sh[1024 + rl * 128 + c4 + 0] = q0; sh[1024 + rl * 128 + c4 + 1] = q1;
    sh[1024 + rl * 128 + c4 + 2] = q2; sh[1024 + rl * 128 + c4 + 3] = q3;
    __syncthreads();
    if (threadIdx.x < 128) {
        float ts = 0.f, tq = 0.f;
        for (int g = 0; g < 8; g++) {
            ts += sh[g * 128 + threadIdx.x];
            tq += sh[1024 + g * 128 + threadIdx.x];
        }
        atomicAdd(&stats[threadIdx.x], ts);
        atomicAdd(&stats[HF + threadIdx.x], tq);
    }
}

// ------- BN fold -------
__global__ void k_foldbias(const float* __restrict__ stats, float cntInv,
                           const float* __restrict__ g, const float* __restrict__ b,
                           const float* __restrict__ W, unsigned short* __restrict__ Wtb,
                           float* __restrict__ biasT) {
    int n = blockIdx.x, k = threadIdx.x;
    float mean = stats[k] * cntInv;
    float var = stats[HF + k] * cntInv - mean * mean;
    float sc = g[k] * rsqrtf(var + EPS);
    float shf = b[k] - mean * sc;
    float wkn = W[k * HF + n];
    Wtb[n * HF + k] = f2bf(sc * wkn);
    __shared__ float red[128];
    red[k] = shf * wkn;
    __syncthreads();
    for (int o = 64; o > 0; o >>= 1) {
        if (k < o) red[k] += red[k + o];
        __syncthreads();
    }
    if (k == 0) biasT[n] = red[0];
}

__global__ void k_scan1(const int* __restrict__ cd, const int* __restrict__ cs,
                        float* __restrict__ dis, int* offs, int* bsum, int n) {
    __shared__ int sh[256];
    int t = threadIdx.x, i = blockIdx.x * 256 + t;
    if (i < n) dis[i] = rsqrtf((float)(1 + cs[i]));
    int v = (i < n) ? cd[i] : 0;
    sh[t] = v; __syncthreads();
    for (int o = 1; o < 256; o <<= 1) {
        int x = (t >= o) ? sh[t - o] : 0;
        __syncthreads();
        sh[t] += x;
        __syncthreads();
    }
    if (i < n) offs[i] = sh[t] - v;   // exclusive within block
    if (t == 255) bsum[blockIdx.x] = sh[255];
}

__global__ void k_scan2(const int* __restrict__ bsum, int* bscan, int nb) {
    __shared__ int sh[256];
    int t = threadIdx.x;
    int v = (t < nb) ? bsum[t] : 0;
    sh[t] = v; __syncthreads();
    for (int o = 1; o < 256; o <<= 1) {
        int x = (t >= o) ? sh[t - o] : 0;
        __syncthreads();
        sh[t] += x;
        __syncthreads();
    }
    if (t < nb) bscan[t] = sh[t] - v;
}

// ---- CSR fill: slot = offsb[d] + bscan[d>>8] + rank[e] (no scan3 pass) ----
__global__ __launch_bounds__(256) void k_fill(const int* __restrict__ ei, int E,
                                              const float* __restrict__ dis,
                                              const int* __restrict__ offsb,
                                              const int* __restrict__ bscan,
                                              const int* __restrict__ rank,
                                              int2* __restrict__ epk) {
    int e = blockIdx.x * 256 + threadIdx.x;
    if (e < E) {
        int s = ei[e], d = ei[E + e];
        epk[offsb[d] + bscan[d >> 8] + rank[e]] =
            make_int2(s, __float_as_int(dis[s] * dis[d]));
    }
}

// ---- feat-layer MFMA GEMM (fp32 x input, bf16 out, fused stats) ----
__global__ __launch_bounds__(256) void k_featg(const float* __restrict__ Ain,
                                               const unsigned short* __restrict__ Wtb,
                                               const float* __restrict__ biasT,
                                               unsigned short* __restrict__ outv,
                                               float* __restrict__ stats, int n) {
    __shared__ float Ls[4][16 * TSTR];
    __shared__ float bsh[128];
    int l = threadIdx.x & 63, w = threadIdx.x >> 6;
    int lr = l & 15, lc = l >> 4;
    int rowbase = blockIdx.x * 128 + w * 32;
    if (threadIdx.x < 128) bsh[threadIdx.x] = biasT[threadIdx.x];

    f32x4 acc[2][8];
#pragma unroll
    for (int rt = 0; rt < 2; rt++)
#pragma unroll
        for (int nt = 0; nt < 8; nt++) acc[rt][nt] = (f32x4){0.f, 0.f, 0.f, 0.f};

    union U { uint4 u; short8 s; };

    for (int ks = 0; ks < 4; ks++) {
        short8 af[2];
#pragma unroll
        for (int rt = 0; rt < 2; rt++) {
            int row = rowbase + rt * 16 + lr;
            if (row < n) {
                const float4* xp = (const float4*)(Ain + (size_t)row * HF + ks * 32 + lc * 8);
                float4 v0 = xp[0], v1 = xp[1];
                short8 a;
                a[0] = (short)f2bf(v0.x); a[1] = (short)f2bf(v0.y);
                a[2] = (short)f2bf(v0.z); a[3] = (short)f2bf(v0.w);
                a[4] = (short)f2bf(v1.x); a[5] = (short)f2bf(v1.y);
                a[6] = (short)f2bf(v1.z); a[7] = (short)f2bf(v1.w);
                af[rt] = a;
            } else af[rt] = (short8){0,0,0,0,0,0,0,0};
        }
#pragma unroll
        for (int nt = 0; nt < 8; nt++) {
            U ub;
            ub.u = *(const uint4*)(Wtb + (size_t)(nt * 16 + lr) * HF + ks * 32 + lc * 8);
            acc[0][nt] = __builtin_amdgcn_mfma_f32_16x16x32_bf16(af[0], ub.s, acc[0][nt], 0, 0, 0);
            acc[1][nt] = __builtin_amdgcn_mfma_f32_16x16x32_bf16(af[1], ub.s, acc[1][nt], 0, 0, 0);
        }
    }
    __syncthreads();

    {   // fused column stats (post bias+relu)
        float s[8], q[8];
#pragma unroll
        for (int nt = 0; nt < 8; nt++) { s[nt] = 0.f; q[nt] = 0.f; }
#pragma unroll
        for (int rt = 0; rt < 2; rt++) {
#pragma unroll
            for (int nt = 0; nt < 8; nt++) {
                float bias = bsh[nt * 16 + lr];
#pragma unroll
                for (int r = 0; r < 4; r++) {
                    int row = rowbase + rt * 16 + lc * 4 + r;
                    if (row < n) {
                        float v = fmaxf(acc[rt][nt][r] + bias, 0.f);
                        s[nt] += v; q[nt] += v * v;
                    }
                }
            }
        }
#pragma unroll
        for (int nt = 0; nt < 8; nt++) {
            s[nt] += __shfl_xor(s[nt], 16);
            q[nt] += __shfl_xor(q[nt], 16);
            s[nt] += __shfl_xor(s[nt], 32);
            q[nt] += __shfl_xor(q[nt], 32);
        }
        if (lc == 0) {
#pragma unroll
            for (int nt = 0; nt < 8; nt++) {
                atomicAdd(&stats[nt * 16 + lr], s[nt]);
                atomicAdd(&stats[HF + nt * 16 + lr], q[nt]);
            }
        }
    }

    float* LsW = Ls[w];
    for (int rt = 0; rt < 2; rt++) {
#pragma unroll
        for (int nt = 0; nt < 8; nt++)
#pragma unroll
            for (int r = 0; r < 4; r++)
                LsW[(lc * 4 + r) * TSTR + nt * 16 + lr] = acc[rt][nt][r];
        __syncthreads();
        int r16 = l >> 2, cc = (l & 3) * 32;
        int row = rowbase + rt * 16 + r16;
        if (row < n) {
            unsigned int o[16];
#pragma unroll
            for (int j = 0; j < 16; j++) {
                float v0 = fmaxf(LsW[r16 * TSTR + cc + 2 * j] + bsh[cc + 2 * j], 0.f);
                float v1 = fmaxf(LsW[r16 * TSTR + cc + 2 * j + 1] + bsh[cc + 2 * j + 1], 0.f);
                o[j] = (unsigned int)f2bf(v0) | ((unsigned int)f2bf(v1) << 16);
            }
            uint4* dst = (uint4*)(outv + (size_t)row * HF + cc);
            dst[0] = make_uint4(o[0], o[1], o[2], o[3]);
            dst[1] = make_uint4(o[4], o[5], o[6], o[7]);
            dst[2] = make_uint4(o[8], o[9], o[10], o[11]);
            dst[3] = make_uint4(o[12], o[13], o[14], o[15]);
        }
        __syncthreads();
    }
}

// ---------------- MFMA GEMM (conv layers): bf16 in -> int8 out + rowscale ----------------
__global__ __launch_bounds__(256) void k_mgemm(const unsigned short* __restrict__ Ain,
                                               const unsigned short* __restrict__ Wtb,
                                               const float* __restrict__ biasT,
                                               unsigned char* __restrict__ outv,
                                               float* __restrict__ rowscl, int n) {
    __shared__ float Ls[4][16 * TSTR];
    __shared__ float bsh[128];
    int l = threadIdx.x & 63, w = threadIdx.x >> 6;
    int lr = l & 15, lc = l >> 4;
    int rowbase = blockIdx.x * 128 + w * 32;
    if (threadIdx.x < 128) bsh[threadIdx.x] = biasT[threadIdx.x];

    f32x4 acc[2][8];
#pragma unroll
    for (int rt = 0; rt < 2; rt++)
#pragma unroll
        for (int nt = 0; nt < 8; nt++) acc[rt][nt] = (f32x4){0.f, 0.f, 0.f, 0.f};

    union U { uint4 u; short8 s; };

    for (int ks = 0; ks < 4; ks++) {
        short8 af[2];
#pragma unroll
        for (int rt = 0; rt < 2; rt++) {
            int row = rowbase + rt * 16 + lr;
            if (row < n) {
                U u;
                u.u = *(const uint4*)(Ain + (size_t)row * HF + ks * 32 + lc * 8);
                af[rt] = u.s;
            } else af[rt] = (short8){0,0,0,0,0,0,0,0};
        }
#pragma unroll
        for (int nt = 0; nt < 8; nt++) {
            U ub;
            ub.u = *(const uint4*)(Wtb + (size_t)(nt * 16 + lr) * HF + ks * 32 + lc * 8);
            acc[0][nt] = __builtin_amdgcn_mfma_f32_16x16x32_bf16(af[0], ub.s, acc[0][nt], 0, 0, 0);
            acc[1][nt] = __builtin_amdgcn_mfma_f32_16x16x32_bf16(af[1], ub.s, acc[1][nt], 0, 0, 0);
        }
    }
    __syncthreads();

    float* LsW = Ls[w];
    for (int rt = 0; rt < 2; rt++) {
#pragma unroll
        for (int nt = 0; nt < 8; nt++)
#pragma unroll
            for (int r = 0; r < 4; r++)
                LsW[(lc * 4 + r) * TSTR + nt * 16 + lr] = acc[rt][nt][r];
        __syncthreads();
        int r16 = l >> 2, cc = (l & 3) * 32;
        int row = rowbase + rt * 16 + r16;
        if (row < n) {
            float v[32];
#pragma unroll
            for (int j = 0; j < 32; j++)
                v[j] = LsW[r16 * TSTR + cc + j] + bsh[cc + j];
            float m = 0.f;
#pragma unroll
            for (int j = 0; j < 32; j++) m = fmaxf(m, fabsf(v[j]));
            m = fmaxf(m, __shfl_xor(m, 1));
            m = fmaxf(m, __shfl_xor(m, 2));
            float inv = (m > 1e-20f) ? 127.f / m : 0.f;
            unsigned int o[8];
#pragma unroll
            for (int j = 0; j < 8; j++)
                o[j] = pk4i8(v[4 * j], v[4 * j + 1], v[4 * j + 2], v[4 * j + 3], inv);
            uint4* dst = (uint4*)(outv + (size_t)row * 128 + cc);
            dst[0] = make_uint4(o[0], o[1], o[2], o[3]);
            dst[1] = make_uint4(o[4], o[5], o[6], o[7]);
            if ((l & 3) == 0) rowscl[row] = m * (1.f / 127.f);
        }
        __syncthreads();
    }
}

// ------- aggregation: LDS-staged CSR (premultiplied weights), offs computed inline -------
template <int STATS>
__global__ __launch_bounds__(256) void k_agg(const unsigned char* __restrict__ B,
                                             const float* __restrict__ rsc,
                                             const int2* __restrict__ epk,
                                             const int* __restrict__ offsb,
                                             const int* __restrict__ bscan,
                                             const int* __restrict__ cnt,
                                             const float* __restrict__ dis,
                                             const float* __restrict__ convb,
                                             unsigned short* __restrict__ out,
                                             float* stats, int n) {
    __shared__ int2 cache[CAP];   // 16 KB; reused as float[4096] for stats
    int t = threadIdx.x;
    int lg = t & 7;
    int nb0 = blockIdx.x * 32;
    int node = nb0 + (t >> 3);
    int endNode = min(nb0 + 32, n);
    int segBase = (nb0 < n) ? (offsb[nb0] + bscan[nb0 >> 8]) : 0;
    int segEnd = (endNode > nb0)
                     ? (offsb[endNode - 1] + bscan[(endNode - 1) >> 8] + cnt[endNode - 1])
                     : segBase;

    for (int idx = segBase + t; idx < segEnd; idx += 256) {
        int li = idx - segBase;
        if (li >= CAP) break;
        int2 p = epk[idx];
        cache[li] = make_int2(p.x, __float_as_int(__int_as_float(p.y) * rsc[p.x]));
    }
    __syncthreads();

    const uint4* Bv = (const uint4*)B;
    float acc[16];
#pragma unroll
    for (int k = 0; k < 16; k++) acc[k] = 0.f;
    float v[16];
    if (node < n) {
        float d = dis[node];
        i8acc16(acc, Bv[(size_t)node * 8 + lg], d * d * rsc[node]);
        int j0 = offsb[node] + bscan[node >> 8], e0 = j0 + cnt[node];
        if (e0 - segBase <= CAP) {
            int li = j0 - segBase, le = e0 - segBase;
            int2 p[8];
#pragma unroll
            for (int u = 0; u < 8; u++) p[u] = (li + u < le) ? cache[li + u] : make_int2(node, 0);
            while (li < le) {
                uint4 g0 = Bv[(size_t)p[0].x * 8 + lg];
                uint4 g1 = Bv[(size_t)p[1].x * 8 + lg];
                uint4 g2 = Bv[(size_t)p[2].x * 8 + lg];
                uint4 g3 = Bv[(size_t)p[3].x * 8 + lg];
                uint4 g4 = Bv[(size_t)p[4].x * 8 + lg];
                uint4 g5 = Bv[(size_t)p[5].x * 8 + lg];
                uint4 g6 = Bv[(size_t)p[6].x * 8 + lg];
                uint4 g7 = Bv[(size_t)p[7].x * 8 + lg];
                int ln = li + 8;
                int2 pn[8];
#pragma unroll
                for (int u = 0; u < 8; u++) pn[u] = (ln + u < le) ? cache[ln + u] : make_int2(node, 0);
                i8acc16(acc, g0, __int_as_float(p[0].y));
                i8acc16(acc, g1, __int_as_float(p[1].y));
                i8acc16(acc, g2, __int_as_float(p[2].y));
                i8acc16(acc, g3, __int_as_float(p[3].y));
                i8acc16(acc, g4, __int_as_float(p[4].y));
                i8acc16(acc, g5, __int_as_float(p[5].y));
                i8acc16(acc, g6, __int_as_float(p[6].y));
                i8acc16(acc, g7, __int_as_float(p[7].y));
#pragma unroll
                for (int u = 0; u < 8; u++) p[u] = pn[u];
                li = ln;
            }
        } else {
            for (int j = j0; j < e0; j++) {
                int2 p = epk[j];
                float wq = __int_as_float(p.y) * rsc[p.x];
                i8acc16(acc, Bv[(size_t)p.x * 8 + lg], wq);
            }
        }
        const float4* cb = (const float4*)convb;
        float4 b0 = cb[lg * 4], b1 = cb[lg * 4 + 1], b2 = cb[lg * 4 + 2], b3 = cb[lg * 4 + 3];
        v[0]  = fmaxf(acc[0]  + b0.x, 0.f); v[1]  = fmaxf(acc[1]  + b0.y, 0.f);
        v[2]  = fmaxf(acc[2]  + b0.z, 0.f); v[3]  = fmaxf(acc[3]  + b0.w, 0.f);
        v[4]  = fmaxf(acc[4]  + b1.x, 0.f); v[5]  = fmaxf(acc[5]  + b1.y, 0.f);
        v[6]  = fmaxf(acc[6]  + b1.z, 0.f); v[7]  = fmaxf(acc[7]  + b1.w, 0.f);
        v[8]  = fmaxf(acc[8]  + b2.x, 0.f); v[9]  = fmaxf(acc[9]  + b2.y, 0.f);
        v[10] = fmaxf(acc[10] + b2.z, 0.f); v[11] = fmaxf(acc[11] + b2.w, 0.f);
        v[12] = fmaxf(acc[12] + b3.x, 0.f); v[13] = fmaxf(acc[13] + b3.y, 0.f);
        v[14] = fmaxf(acc[14] + b3.z, 0.f); v[15] = fmaxf(acc[15] + b3.w, 0.f);
        uint4 o0, o1;
        o0.x = (unsigned int)f2bf(v[0])  | ((unsigned int)f2bf(v[1])  << 16);
        o0.y = (unsigned int)f2bf(v[2])  | ((unsigned int)f2bf(v[3])  << 16);
        o0.z = (unsigned int)f2bf(v[4])  | ((unsigned int)f2bf(v[5])  << 16);
        o0.w = (unsigned int)f2bf(v[6])  | ((unsigned int)f2bf(v[7])  << 16);
        o1.x = (unsigned int)f2bf(v[8])  | ((unsigned int)f2bf(v[9])  << 16);
        o1.y = (unsigned int)f2bf(v[10]) | ((unsigned int)f2bf(v[11]) << 16);
        o1.z = (unsigned int)f2bf(v[12]) | ((unsigned int)f2bf(v[13]) << 16);
        o1.w = (unsigned int)f2bf(v[14]) | ((unsigned int)f2bf(v[15]) << 16);
        uint4* op = (uint4*)out + (size_t)node * 16 + lg * 2;
        op[0] = o0; op[1] = o1;
    } else {
#pragma unroll
        for (int k = 0; k < 16; k++) v[k] = 0.f;
    }
    if (STATS) {
        __syncthreads();
        float* sh = (float*)cache;
        int nb = t >> 3;
#pragma unroll
        for (int k = 0; k < 16; k++) sh[nb * 128 + lg * 16 + k] = v[k];
        __syncthreads();
        if (t < 128) {
            float ts = 0.f, tq = 0.f;
            for (int g = 0; g < 32; g++) {
                float val = sh[g * 128 + t];
                ts += val; tq += val * val;
            }
            atomicAdd(&stats[t], ts);
            atomicAdd(&stats[HF + t], tq);
        }
    }
}

// ---------------- global add pool ----------------
__global__ __launch_bounds__(256) void k_pool(const unsigned short* __restrict__ A,
                                              const int* __restrict__ batch,
                                              float* gpool, int n) {
    int g = blockIdx.x >> 2, part = blockIdx.x & 3;
    int lo, hi;
    {
        int l = 0, r = n;
        while (l < r) { int m = (l + r) >> 1; if (batch[m] < g) l = m + 1; else r = m; }
        lo = l;
    }
    {
        int l = lo, r = n;
        while (l < r) { int m = (l + r) >> 1; if (batch[m] < g + 1) l = m + 1; else r = m; }
        hi = l;
    }
    int cntg = hi - lo;
    if (cntg <= 0) return;
    int per = (cntg + 3) >> 2;
    int s = lo + part * per, e = min(s + per, hi);
    int c2 = threadIdx.x & 63;
    int rl = threadIdx.x >> 6;
    float a0 = 0.f, a1 = 0.f;
    for (int i = s + rl; i < e; i += 4) {
        unsigned int u = ((const unsigned int*)(A + (size_t)i * HF))[c2];
        a0 += bf2f((unsigned short)(u & 0xFFFFu));
        a1 += bf2f((unsigned short)(u >> 16));
    }
    __shared__ float sh[512];
    sh[rl * 128 + c2 * 2] = a0;
    sh[rl * 128 + c2 * 2 + 1] = a1;
    __syncthreads();
    if (threadIdx.x < 128 && s < hi) {
        float s4 = sh[threadIdx.x] + sh[128 + threadIdx.x] + sh[256 + threadIdx.x] + sh[384 + threadIdx.x];
        atomicAdd(&gpool[g * HF + threadIdx.x], s4);
    }
}

// ---------------- fused bnsmall + fc (one block per graph row) ----------------
__global__ __launch_bounds__(128) void k_bnfc(const float* __restrict__ gpool,
                                              const float* __restrict__ g,
                                              const float* __restrict__ b,
                                              const float* __restrict__ Wfc,
                                              const float* __restrict__ bfc,
                                              float* __restrict__ G2) {
    int c = threadIdx.x, r = blockIdx.x;
    float s = 0.f, q = 0.f;
    for (int rr = 0; rr < GG; rr++) {
        float v = gpool[rr * HF + c];
        s += v; q += v * v;
    }
    float mean = s / GG;
    float var = q / GG - mean * mean;
    float sc = g[c] * rsqrtf(var + EPS), sh = b[c] - mean * sc;
    __shared__ float row[HF];
    row[c] = gpool[r * HF + c] * sc + sh;
    __syncthreads();
    float acc = bfc[c];
    for (int k = 0; k < HF; k++) acc += row[k] * Wfc[k * HF + c];
    G2[r * HF + c] = fmaxf(acc, 0.f);
}

__global__ void k_head2(const float* __restrict__ G2, const float* __restrict__ g,
                        const float* __restrict__ b, const float* __restrict__ Wcls,
                        const float* __restrict__ bcls, float* __restrict__ scratch,
                        float* __restrict__ outp) {
    __shared__ float Ls[GG * HF];
    int c = threadIdx.x;
    float s = 0.f, q = 0.f;
    for (int r = 0; r < GG; r++) { float v = G2[r * HF + c]; s += v; q += v * v; }
    float mean = s / GG;
    float var = q / GG - mean * mean;
    float sc = g[c] * rsqrtf(var + EPS), sh = b[c] - mean * sc;
    for (int r = 0; r < GG; r++) Ls[r * HF + c] = G2[r * HF + c] * sc + sh;
    __syncthreads();
    for (int o = c; o < GG * CC; o += HF) {
        int r = o / CC, j = o % CC;
        float acc = bcls[j];
        for (int k = 0; k < HF; k++) acc += Ls[r * HF + k] * Wcls[k * CC + j];
        scratch[o] = acc;
    }
    __threadfence_block();
    __syncthreads();
    int r = c;
    float m = -1e30f;
    for (int j = 0; j < CC; j++) m = fmaxf(m, scratch[r * CC + j]);
    float se = 0.f;
    for (int j = 0; j < CC; j++) se += expf(scratch[r * CC + j] - m);
    float ls = logf(se);
    for (int j = 0; j < CC; j++) outp[r * CC + j] = scratch[r * CC + j] - m - ls;
}

extern "C" void kernel_launch(void* const* d_in, const int* in_sizes, int n_in,
                              void* d_out, int out_size, void* d_ws, size_t ws_size,
                              hipStream_t stream) {
    const float* x         = (const float*)d_in[0];
    const int*   ei        = (const int*)d_in[1];
    const int*   batch     = (const int*)d_in[2];
    const float* bn_feat_g = (const float*)d_in[3];
    const float* bn_feat_b = (const float*)d_in[4];
    const float* W_feat    = (const float*)d_in[5];
    const float* conv_bn_g = (const float*)d_in[6];
    const float* conv_bn_b = (const float*)d_in[7];
    const float* conv_W    = (const float*)d_in[8];
    const float* conv_b    = (const float*)d_in[9];
    const float* bn_fc_g   = (const float*)d_in[10];
    const float* bn_fc_b   = (const float*)d_in[11];
    const float* W_fc      = (const float*)d_in[12];
    const float* b_fc      = (const float*)d_in[13];
    const float* bn_hid_g  = (const float*)d_in[14];
    const float* bn_hid_b  = (const float*)d_in[15];
    const float* W_cls     = (const float*)d_in[16];
    const float* b_cls     = (const float*)d_in[17];
    float* outp = (float*)d_out;

    int N = in_sizes[0] / HF;
    int E = in_sizes[1] / 2;

    char* w = (char*)d_ws;
    size_t off = 0;
    auto al = [&](size_t bytes) -> void* {
        off = (off + 255) & ~(size_t)255;
        void* p = w + off;
        off += bytes;
        return p;
    };
    unsigned short* A  = (unsigned short*)al((size_t)N * HF * 2);   // bf16 node features
    unsigned char*  Bf = (unsigned char*)al((size_t)N * HF);        // int8 gather table
    float* rowscl = (float*)al((size_t)N * 4);
    int2*  epk    = (int2*)al((size_t)E * 8);
    int*   rank   = (int*)al((size_t)E * 4);
    float* dis    = (float*)al((size_t)N * 4);
    int*   offsb  = (int*)al((size_t)N * 4);
    unsigned short* Wtb = (unsigned short*)al(HF * HF * 2);
    float* biasT  = (float*)al(HF * 4);
    int*   bsum   = (int*)al(1024);
    int*   bscan  = (int*)al(1024);
    float* Gbn    = (float*)al(GG * HF * 4);
    float* G2     = (float*)al(GG * HF * 4);
    // zeroed region
    size_t z0 = (off + 255) & ~(size_t)255;
    off = z0;
    int*   cs    = (int*)al((size_t)N * 4);
    int*   cd    = (int*)al((size_t)N * 4);
    float* Sx    = (float*)al(2 * HF * 4);
    float* S0    = (float*)al(2 * HF * 4);
    float* S1    = (float*)al(2 * HF * 4);
    float* S2    = (float*)al(2 * HF * 4);
    float* gpool = (float*)al(GG * HF * 4);
    size_t zbytes = off - z0;
    hipMemsetAsync(w + z0, 0, zbytes, stream);

    int nbE = (E + 255) / 256;
    int nbN = (N + 255) / 256;
    int gemmGrid = (N + 127) / 128;

    // feature chain prefix (independent of graph)
    k_colstats<<<400, 256, 0, stream>>>(x, Sx, N);
    k_foldbias<<<HF, HF, 0, stream>>>(Sx, 1.0f / N, bn_feat_g, bn_feat_b, W_feat, Wtb, biasT);
    k_featg<<<gemmGrid, 256, 0, stream>>>(x, Wtb, biasT, A, S0, N);

    // graph build (all standalone, natural occupancy)
    k_count<<<nbE, 256, 0, stream>>>(ei, E, cs, cd, rank);
    k_scan1<<<nbN, 256, 0, stream>>>(cd, cs, dis, offsb, bsum, N);
    k_scan2<<<1, 256, 0, stream>>>(bsum, bscan, nbN);
    k_fill<<<nbE, 256, 0, stream>>>(ei, E, dis, offsb, bscan, rank, epk);

    float* Sarr[3] = {S0, S1, S2};
    for (int i = 0; i < 3; i++) {
        k_foldbias<<<HF, HF, 0, stream>>>(Sarr[i], 1.0f / N, conv_bn_g + i * HF, conv_bn_b + i * HF,
                                          conv_W + (size_t)i * HF * HF, Wtb, biasT);
        k_mgemm<<<gemmGrid, 256, 0, stream>>>(A, Wtb, biasT, Bf, rowscl, N);
        if (i < 2)
            k_agg<1><<<(N + 31) / 32, 256, 0, stream>>>(Bf, rowscl, epk, offsb, bscan, cd, dis,
                                                        conv_b + i * HF, A, Sarr[i + 1], N);
        else
            k_agg<0><<<(N + 31) / 32, 256, 0, stream>>>(Bf, rowscl, epk, offsb, bscan, cd, dis,
                                                        conv_b + i * HF, A, nullptr, N);
    }

    // pool + head
    k_pool<<<GG * 4, 256, 0, stream>>>(A, batch, gpool, N);
    k_bnfc<<<GG, HF, 0, stream>>>(gpool, bn_fc_g, bn_fc_b, W_fc, b_fc, G2);
    k_head2<<<1, HF, 0, stream>>>(G2, bn_hid_g, bn_hid_b, W_cls, b_cls, Gbn, outp);
}

// Round 20
// 388.560 us; speedup vs baseline: 1.0778x; 1.0554x over previous
//
#include <hip/hip_runtime.h>
#include <hip/hip_bf16.h>

#define HF 128
#define GG 128
#define CC 10
#define EPS 1e-5f
#define TSTR 129          // padded LDS transpose stride (floats)
#define CAP 2048          // per-block cached CSR entries (16 KB)

typedef __attribute__((ext_vector_type(8))) short short8;
typedef __attribute__((ext_vector_type(4))) float f32x4;

__device__ inline unsigned short f2bf(float f) {
    unsigned int u = __float_as_uint(f);
    return (unsigned short)((u + 0x7FFFu + ((u >> 16) & 1u)) >> 16);
}

__device__ inline float bf2f(unsigned short h) {
    return __uint_as_float(((unsigned int)h) << 16);
}

// acc[0..7] += w * sext_int8x8(x,y)   (signed int8, exact decode)
__device__ inline void i8acc(float* acc, unsigned int x, unsigned int y, float w) {
    acc[0] = fmaf(w, (float)((int)(x << 24) >> 24), acc[0]);
    acc[1] = fmaf(w, (float)((int)(x << 16) >> 24), acc[1]);
    acc[2] = fmaf(w, (float)((int)(x << 8) >> 24), acc[2]);
    acc[3] = fmaf(w, (float)((int)x >> 24), acc[3]);
    acc[4] = fmaf(w, (float)((int)(y << 24) >> 24), acc[4]);
    acc[5] = fmaf(w, (float)((int)(y << 16) >> 24), acc[5]);
    acc[6] = fmaf(w, (float)((int)(y << 8) >> 24), acc[6]);
    acc[7] = fmaf(w, (float)((int)y >> 24), acc[7]);
}

__device__ inline void i8acc16(float* acc, uint4 u, float w) {
    i8acc(acc, u.x, u.y, w);
    i8acc(acc + 8, u.z, u.w, w);
}

__device__ inline unsigned int pk4i8(float a, float b, float c, float d, float inv) {
    int q0 = (int)rintf(a * inv), q1 = (int)rintf(b * inv);
    int q2 = (int)rintf(c * inv), q3 = (int)rintf(d * inv);
    return (unsigned int)(q0 & 255) | ((unsigned int)(q1 & 255) << 8) |
           ((unsigned int)(q2 & 255) << 16) | ((unsigned int)(q3 & 255) << 24);
}

// ---------------- BN stats over x + bf16 copy ----------------
__global__ __launch_bounds__(256) void k_colstats(const float* __restrict__ X, float* stats,
                                                  unsigned short* __restrict__ xb, int n) {
    int c4 = (threadIdx.x & 31) * 4;
    int rl = threadIdx.x >> 5;
    float s0 = 0.f, s1 = 0.f, s2 = 0.f, s3 = 0.f;
    float q0 = 0.f, q1 = 0.f, q2 = 0.f, q3 = 0.f;
    for (int i = blockIdx.x * 8 + rl; i < n; i += gridDim.x * 8) {
        float4 v = *(const float4*)(X + (size_t)i * HF + c4);
        s0 += v.x; q0 += v.x * v.x;
        s1 += v.y; q1 += v.y * v.y;
        s2 += v.z; q2 += v.z * v.z;
        s3 += v.w; q3 += v.w * v.w;
        ushort4 o;
        o.x = f2bf(v.x); o.y = f2bf(v.y); o.z = f2bf(v.z); o.w = f2bf(v.w);
        *(ushort4*)(xb + (size_t)i * HF + c4) = o;
    }
    __shared__ float sh[2048];
    sh[rl * 128 + c4 + 0] = s0; sh[rl * 128 + c4 + 1] = s1;
    sh[rl * 128 + c4 + 2] = s2; sh[rl * 128 + c4 + 3] = s3;
    sh[1024 + rl * 128 + c4 + 0] = q0; sh[1024 + rl * 128 + c4 + 1] = q1;
    sh[1024 + rl * 128 + c4 + 2] = q2; sh[1024 + rl * 128 + c4 + 3] = q3;
    __syncthreads();
    if (threadIdx.x < 128) {
        float ts = 0.f, tq = 0.f;
        for (int g = 0; g < 8; g++) {
            ts += sh[g * 128 + threadIdx.x];
            tq += sh[1024 + g * 128 + threadIdx.x];
        }
        atomicAdd(&stats[threadIdx.x], ts);
        atomicAdd(&stats[HF + threadIdx.x], tq);
    }
}

// ------- BN fold -------
__global__ void k_foldbias(const float* __restrict__ stats, float cntInv,
                           const float* __restrict__ g, const float* __restrict__ b,
                           const float* __restrict__ W, unsigned short* __restrict__ Wtb,
                           float* __restrict__ biasT) {
    int n = blockIdx.x, k = threadIdx.x;
    float mean = stats[k] * cntInv;
    float var = stats[HF + k] * cntInv - mean * mean;
    float sc = g[k] * rsqrtf(var + EPS);
    float shf = b[k] - mean * sc;
    float wkn = W[k * HF + n];
    Wtb[n * HF + k] = f2bf(sc * wkn);
    __shared__ float red[128];
    red[k] = shf * wkn;
    __syncthreads();
    for (int o = 64; o > 0; o >>= 1) {
        if (k < o) red[k] += red[k + o];
        __syncthreads();
    }
    if (k == 0) biasT[n] = red[0];
}

// ---- fused: feat-layer MFMA GEMM on bf16 xb (blocks [0,gB)) + edge count/rank atomics ----
__global__ __launch_bounds__(256) void k_featfuse(const unsigned short* __restrict__ Ain,
                                                  const unsigned short* __restrict__ Wtb,
                                                  const float* __restrict__ biasT,
                                                  unsigned short* __restrict__ outv,
                                                  float* __restrict__ stats, int n, int gB,
                                                  const int* __restrict__ ei, int E,
                                                  int* cs, int* cd, int* __restrict__ rank) {
    __shared__ float Ls[4][16 * TSTR];
    __shared__ float bsh[128];
    if ((int)blockIdx.x >= gB) {
        int e = ((int)blockIdx.x - gB) * 256 + threadIdx.x;
        if (e < E) {
            atomicAdd(&cs[ei[e]], 1);
            rank[e] = atomicAdd(&cd[ei[E + e]], 1);
        }
        return;
    }
    int l = threadIdx.x & 63, w = threadIdx.x >> 6;
    int lr = l & 15, lc = l >> 4;
    int rowbase = blockIdx.x * 128 + w * 32;
    if (threadIdx.x < 128) bsh[threadIdx.x] = biasT[threadIdx.x];

    f32x4 acc[2][8];
#pragma unroll
    for (int rt = 0; rt < 2; rt++)
#pragma unroll
        for (int nt = 0; nt < 8; nt++) acc[rt][nt] = (f32x4){0.f, 0.f, 0.f, 0.f};

    union U { uint4 u; short8 s; };

    for (int ks = 0; ks < 4; ks++) {
        short8 af[2];
#pragma unroll
        for (int rt = 0; rt < 2; rt++) {
            int row = rowbase + rt * 16 + lr;
            if (row < n) {
                U u;
                u.u = *(const uint4*)(Ain + (size_t)row * HF + ks * 32 + lc * 8);
                af[rt] = u.s;
            } else af[rt] = (short8){0,0,0,0,0,0,0,0};
        }
#pragma unroll
        for (int nt = 0; nt < 8; nt++) {
            U ub;
            ub.u = *(const uint4*)(Wtb + (size_t)(nt * 16 + lr) * HF + ks * 32 + lc * 8);
            acc[0][nt] = __builtin_amdgcn_mfma_f32_16x16x32_bf16(af[0], ub.s, acc[0][nt], 0, 0, 0);
            acc[1][nt] = __builtin_amdgcn_mfma_f32_16x16x32_bf16(af[1], ub.s, acc[1][nt], 0, 0, 0);
        }
    }
    __syncthreads();   // bsh ready

    {   // fused column stats (post bias+relu)
        float s[8], q[8];
#pragma unroll
        for (int nt = 0; nt < 8; nt++) { s[nt] = 0.f; q[nt] = 0.f; }
#pragma unroll
        for (int rt = 0; rt < 2; rt++) {
#pragma unroll
            for (int nt = 0; nt < 8; nt++) {
                float bias = bsh[nt * 16 + lr];
#pragma unroll
                for (int r = 0; r < 4; r++) {
                    int row = rowbase + rt * 16 + lc * 4 + r;
                    if (row < n) {
                        float v = fmaxf(acc[rt][nt][r] + bias, 0.f);
                        s[nt] += v; q[nt] += v * v;
                    }
                }
            }
        }
#pragma unroll
        for (int nt = 0; nt < 8; nt++) {
            s[nt] += __shfl_xor(s[nt], 16);
            q[nt] += __shfl_xor(q[nt], 16);
            s[nt] += __shfl_xor(s[nt], 32);
            q[nt] += __shfl_xor(q[nt], 32);
        }
        if (lc == 0) {
#pragma unroll
            for (int nt = 0; nt < 8; nt++) {
                atomicAdd(&stats[nt * 16 + lr], s[nt]);
                atomicAdd(&stats[HF + nt * 16 + lr], q[nt]);
            }
        }
    }

    // transpose via LDS (padded stride), coalesced bf16 stores
    float* LsW = Ls[w];
    for (int rt = 0; rt < 2; rt++) {
#pragma unroll
        for (int nt = 0; nt < 8; nt++)
#pragma unroll
            for (int r = 0; r < 4; r++)
                LsW[(lc * 4 + r) * TSTR + nt * 16 + lr] = acc[rt][nt][r];
        __syncthreads();
        int r16 = l >> 2, cc = (l & 3) * 32;
        int row = rowbase + rt * 16 + r16;
        if (row < n) {
            unsigned int o[16];
#pragma unroll
            for (int j = 0; j < 16; j++) {
                float v0 = fmaxf(LsW[r16 * TSTR + cc + 2 * j] + bsh[cc + 2 * j], 0.f);
                float v1 = fmaxf(LsW[r16 * TSTR + cc + 2 * j + 1] + bsh[cc + 2 * j + 1], 0.f);
                o[j] = (unsigned int)f2bf(v0) | ((unsigned int)f2bf(v1) << 16);
            }
            uint4* dst = (uint4*)(outv + (size_t)row * HF + cc);
            dst[0] = make_uint4(o[0], o[1], o[2], o[3]);
            dst[1] = make_uint4(o[4], o[5], o[6], o[7]);
            dst[2] = make_uint4(o[8], o[9], o[10], o[11]);
            dst[3] = make_uint4(o[12], o[13], o[14], o[15]);
        }
        __syncthreads();
    }
}

__global__ void k_scan1(const int* __restrict__ cd, const int* __restrict__ cs,
                        float* __restrict__ dis, int* offs, int* bsum, int n) {
    __shared__ int sh[256];
    int t = threadIdx.x, i = blockIdx.x * 256 + t;
    if (i < n) dis[i] = rsqrtf((float)(1 + cs[i]));
    int v = (i < n) ? cd[i] : 0;
    sh[t] = v; __syncthreads();
    for (int o = 1; o < 256; o <<= 1) {
        int x = (t >= o) ? sh[t - o] : 0;
        __syncthreads();
        sh[t] += x;
        __syncthreads();
    }
    if (i < n) offs[i] = sh[t] - v;   // exclusive within block
    if (t == 255) bsum[blockIdx.x] = sh[255];
}

__global__ void k_scan2(const int* __restrict__ bsum, int* bscan, int nb) {
    __shared__ int sh[256];
    int t = threadIdx.x;
    int v = (t < nb) ? bsum[t] : 0;
    sh[t] = v; __syncthreads();
    for (int o = 1; o < 256; o <<= 1) {
        int x = (t >= o) ? sh[t - o] : 0;
        __syncthreads();
        sh[t] += x;
        __syncthreads();
    }
    if (t < nb) bscan[t] = sh[t] - v;
}

// ---------------- MFMA GEMM (conv layers) + optional fused CSR fill ----------------
// Fill computes offs inline: offsb[d] + bscan[d>>8] + rank[e]  (no scan3 pass).
template <int RELU, int STATS, int OUTQ, int FILL>
__global__ __launch_bounds__(256) void k_mgemm(const unsigned short* __restrict__ Ain,
                                               const unsigned short* __restrict__ Wtb,
                                               const float* __restrict__ biasT,
                                               void* __restrict__ outv,
                                               float* __restrict__ rowscl,
                                               int n, float* stats, int gB,
                                               const int* __restrict__ ei, int E,
                                               const float* __restrict__ dis,
                                               const int* __restrict__ offsb,
                                               const int* __restrict__ bscan,
                                               const int* __restrict__ rank,
                                               int2* __restrict__ epk) {
    __shared__ float Ls[4][16 * TSTR];
    __shared__ float bsh[128];
    if (FILL) {
        if ((int)blockIdx.x >= gB) {
            int e = ((int)blockIdx.x - gB) * 256 + threadIdx.x;
            if (e < E) {
                int s = ei[e], d = ei[E + e];
                epk[offsb[d] + bscan[d >> 8] + rank[e]] =
                    make_int2(s, __float_as_int(dis[s] * dis[d]));
            }
            return;
        }
    }
    int l = threadIdx.x & 63, w = threadIdx.x >> 6;
    int lr = l & 15, lc = l >> 4;
    int rowbase = blockIdx.x * 128 + w * 32;
    if (threadIdx.x < 128) bsh[threadIdx.x] = biasT[threadIdx.x];

    f32x4 acc[2][8];
#pragma unroll
    for (int rt = 0; rt < 2; rt++)
#pragma unroll
        for (int nt = 0; nt < 8; nt++) acc[rt][nt] = (f32x4){0.f, 0.f, 0.f, 0.f};

    union U { uint4 u; short8 s; };

    for (int ks = 0; ks < 4; ks++) {
        short8 af[2];
#pragma unroll
        for (int rt = 0; rt < 2; rt++) {
            int row = rowbase + rt * 16 + lr;
            if (row < n) {
                U u;
                u.u = *(const uint4*)(Ain + (size_t)row * HF + ks * 32 + lc * 8);
                af[rt] = u.s;
            } else af[rt] = (short8){0,0,0,0,0,0,0,0};
        }
#pragma unroll
        for (int nt = 0; nt < 8; nt++) {
            U ub;
            ub.u = *(const uint4*)(Wtb + (size_t)(nt * 16 + lr) * HF + ks * 32 + lc * 8);
            acc[0][nt] = __builtin_amdgcn_mfma_f32_16x16x32_bf16(af[0], ub.s, acc[0][nt], 0, 0, 0);
            acc[1][nt] = __builtin_amdgcn_mfma_f32_16x16x32_bf16(af[1], ub.s, acc[1][nt], 0, 0, 0);
        }
    }
    __syncthreads();

    if (STATS) {
        float s[8], q[8];
#pragma unroll
        for (int nt = 0; nt < 8; nt++) { s[nt] = 0.f; q[nt] = 0.f; }
#pragma unroll
        for (int rt = 0; rt < 2; rt++) {
#pragma unroll
            for (int nt = 0; nt < 8; nt++) {
                float bias = bsh[nt * 16 + lr];
#pragma unroll
                for (int r = 0; r < 4; r++) {
                    int row = rowbase + rt * 16 + lc * 4 + r;
                    if (row < n) {
                        float v = acc[rt][nt][r] + bias;
                        if (RELU) v = fmaxf(v, 0.f);
                        s[nt] += v; q[nt] += v * v;
                    }
                }
            }
        }
#pragma unroll
        for (int nt = 0; nt < 8; nt++) {
            s[nt] += __shfl_xor(s[nt], 16);
            q[nt] += __shfl_xor(q[nt], 16);
            s[nt] += __shfl_xor(s[nt], 32);
            q[nt] += __shfl_xor(q[nt], 32);
        }
        if (lc == 0) {
#pragma unroll
            for (int nt = 0; nt < 8; nt++) {
                atomicAdd(&stats[nt * 16 + lr], s[nt]);
                atomicAdd(&stats[HF + nt * 16 + lr], q[nt]);
            }
        }
    }

    float* LsW = Ls[w];
    for (int rt = 0; rt < 2; rt++) {
#pragma unroll
        for (int nt = 0; nt < 8; nt++)
#pragma unroll
            for (int r = 0; r < 4; r++)
                LsW[(lc * 4 + r) * TSTR + nt * 16 + lr] = acc[rt][nt][r];
        __syncthreads();
        int r16 = l >> 2, cc = (l & 3) * 32;
        int row = rowbase + rt * 16 + r16;
        if (row < n) {
            float v[32];
#pragma unroll
            for (int j = 0; j < 32; j++) {
                float tv = LsW[r16 * TSTR + cc + j] + bsh[cc + j];
                if (RELU) tv = fmaxf(tv, 0.f);
                v[j] = tv;
            }
            if (OUTQ) {
                float m = 0.f;
#pragma unroll
                for (int j = 0; j < 32; j++) m = fmaxf(m, fabsf(v[j]));
                m = fmaxf(m, __shfl_xor(m, 1));
                m = fmaxf(m, __shfl_xor(m, 2));
                float inv = (m > 1e-20f) ? 127.f / m : 0.f;
                unsigned int o[8];
#pragma unroll
                for (int j = 0; j < 8; j++)
                    o[j] = pk4i8(v[4 * j], v[4 * j + 1], v[4 * j + 2], v[4 * j + 3], inv);
                uint4* dst = (uint4*)((unsigned char*)outv + (size_t)row * 128 + cc);
                dst[0] = make_uint4(o[0], o[1], o[2], o[3]);
                dst[1] = make_uint4(o[4], o[5], o[6], o[7]);
                if ((l & 3) == 0) rowscl[row] = m * (1.f / 127.f);
            } else {
                unsigned int o[16];
#pragma unroll
                for (int j = 0; j < 16; j++)
                    o[j] = (unsigned int)f2bf(v[2 * j]) | ((unsigned int)f2bf(v[2 * j + 1]) << 16);
                uint4* dst = (uint4*)((unsigned short*)outv + (size_t)row * HF + cc);
                dst[0] = make_uint4(o[0], o[1], o[2], o[3]);
                dst[1] = make_uint4(o[4], o[5], o[6], o[7]);
                dst[2] = make_uint4(o[8], o[9], o[10], o[11]);
                dst[3] = make_uint4(o[12], o[13], o[14], o[15]);
            }
        }
        __syncthreads();
    }
}

// ------- aggregation: LDS-staged CSR (premultiplied weights), offs computed inline -------
template <int STATS>
__global__ __launch_bounds__(256) void k_agg(const unsigned char* __restrict__ B,
                                             const float* __restrict__ rsc,
                                             const int2* __restrict__ epk,
                                             const int* __restrict__ offsb,
                                             const int* __restrict__ bscan,
                                             const int* __restrict__ cnt,
                                             const float* __restrict__ dis,
                                             const float* __restrict__ convb,
                                             unsigned short* __restrict__ out,
                                             float* stats, int n) {
    __shared__ int2 cache[CAP];   // 16 KB; reused as float[4096] for stats
    int t = threadIdx.x;
    int lg = t & 7;
    int nb0 = blockIdx.x * 32;
    int node = nb0 + (t >> 3);
    int endNode = min(nb0 + 32, n);
    int segBase = (nb0 < n) ? (offsb[nb0] + bscan[nb0 >> 8]) : 0;
    int segEnd = (endNode > nb0)
                     ? (offsb[endNode - 1] + bscan[(endNode - 1) >> 8] + cnt[endNode - 1])
                     : segBase;

    for (int idx = segBase + t; idx < segEnd; idx += 256) {
        int li = idx - segBase;
        if (li >= CAP) break;
        int2 p = epk[idx];
        cache[li] = make_int2(p.x, __float_as_int(__int_as_float(p.y) * rsc[p.x]));
    }
    __syncthreads();

    const uint4* Bv = (const uint4*)B;
    float acc[16];
#pragma unroll
    for (int k = 0; k < 16; k++) acc[k] = 0.f;
    float v[16];
    if (node < n) {
        float d = dis[node];
        i8acc16(acc, Bv[(size_t)node * 8 + lg], d * d * rsc[node]);
        int j0 = offsb[node] + bscan[node >> 8], e0 = j0 + cnt[node];
        if (e0 - segBase <= CAP) {
            int li = j0 - segBase, le = e0 - segBase;
            int2 p[8];
#pragma unroll
            for (int u = 0; u < 8; u++) p[u] = (li + u < le) ? cache[li + u] : make_int2(node, 0);
            while (li < le) {
                uint4 g0 = Bv[(size_t)p[0].x * 8 + lg];
                uint4 g1 = Bv[(size_t)p[1].x * 8 + lg];
                uint4 g2 = Bv[(size_t)p[2].x * 8 + lg];
                uint4 g3 = Bv[(size_t)p[3].x * 8 + lg];
                uint4 g4 = Bv[(size_t)p[4].x * 8 + lg];
                uint4 g5 = Bv[(size_t)p[5].x * 8 + lg];
                uint4 g6 = Bv[(size_t)p[6].x * 8 + lg];
                uint4 g7 = Bv[(size_t)p[7].x * 8 + lg];
                int ln = li + 8;
                int2 pn[8];
#pragma unroll
                for (int u = 0; u < 8; u++) pn[u] = (ln + u < le) ? cache[ln + u] : make_int2(node, 0);
                i8acc16(acc, g0, __int_as_float(p[0].y));
                i8acc16(acc, g1, __int_as_float(p[1].y));
                i8acc16(acc, g2, __int_as_float(p[2].y));
                i8acc16(acc, g3, __int_as_float(p[3].y));
                i8acc16(acc, g4, __int_as_float(p[4].y));
                i8acc16(acc, g5, __int_as_float(p[5].y));
                i8acc16(acc, g6, __int_as_float(p[6].y));
                i8acc16(acc, g7, __int_as_float(p[7].y));
#pragma unroll
                for (int u = 0; u < 8; u++) p[u] = pn[u];
                li = ln;
            }
        } else {
            for (int j = j0; j < e0; j++) {
                int2 p = epk[j];
                float wq = __int_as_float(p.y) * rsc[p.x];
                i8acc16(acc, Bv[(size_t)p.x * 8 + lg], wq);
            }
        }
        const float4* cb = (const float4*)convb;
        float4 b0 = cb[lg * 4], b1 = cb[lg * 4 + 1], b2 = cb[lg * 4 + 2], b3 = cb[lg * 4 + 3];
        v[0]  = fmaxf(acc[0]  + b0.x, 0.f); v[1]  = fmaxf(acc[1]  + b0.y, 0.f);
        v[2]  = fmaxf(acc[2]  + b0.z, 0.f); v[3]  = fmaxf(acc[3]  + b0.w, 0.f);
        v[4]  = fmaxf(acc[4]  + b1.x, 0.f); v[5]  = fmaxf(acc[5]  + b1.y, 0.f);
        v[6]  = fmaxf(acc[6]  + b1.z, 0.f); v[7]  = fmaxf(acc[7]  + b1.w, 0.f);
        v[8]  = fmaxf(acc[8]  + b2.x, 0.f); v[9]  = fmaxf(acc[9]  + b2.y, 0.f);
        v[10] = fmaxf(acc[10] + b2.z, 0.f); v[11] = fmaxf(acc[11] + b2.w, 0.f);
        v[12] = fmaxf(acc[12] + b3.x, 0.f); v[13] = fmaxf(acc[13] + b3.y, 0.f);
        v[14] = fmaxf(acc[14] + b3.z, 0.f); v[15] = fmaxf(acc[15] + b3.w, 0.f);
        uint4 o0, o1;
        o0.x = (unsigned int)f2bf(v[0])  | ((unsigned int)f2bf(v[1])  << 16);
        o0.y = (unsigned int)f2bf(v[2])  | ((unsigned int)f2bf(v[3])  << 16);
        o0.z = (unsigned int)f2bf(v[4])  | ((unsigned int)f2bf(v[5])  << 16);
        o0.w = (unsigned int)f2bf(v[6])  | ((unsigned int)f2bf(v[7])  << 16);
        o1.x = (unsigned int)f2bf(v[8])  | ((unsigned int)f2bf(v[9])  << 16);
        o1.y = (unsigned int)f2bf(v[10]) | ((unsigned int)f2bf(v[11]) << 16);
        o1.z = (unsigned int)f2bf(v[12]) | ((unsigned int)f2bf(v[13]) << 16);
        o1.w = (unsigned int)f2bf(v[14]) | ((unsigned int)f2bf(v[15]) << 16);
        uint4* op = (uint4*)out + (size_t)node * 16 + lg * 2;
        op[0] = o0; op[1] = o1;
    } else {
#pragma unroll
        for (int k = 0; k < 16; k++) v[k] = 0.f;
    }
    if (STATS) {
        __syncthreads();
        float* sh = (float*)cache;
        int nb = t >> 3;
#pragma unroll
        for (int k = 0; k < 16; k++) sh[nb * 128 + lg * 16 + k] = v[k];
        __syncthreads();
        if (t < 128) {
            float ts = 0.f, tq = 0.f;
            for (int g = 0; g < 32; g++) {
                float val = sh[g * 128 + t];
                ts += val; tq += val * val;
            }
            atomicAdd(&stats[t], ts);
            atomicAdd(&stats[HF + t], tq);
        }
    }
}

// ---------------- global add pool ----------------
__global__ __launch_bounds__(256) void k_pool(const unsigned short* __restrict__ A,
                                              const int* __restrict__ batch,
                                              float* gpool, int n) {
    int g = blockIdx.x >> 2, part = blockIdx.x & 3;
    int lo, hi;
    {
        int l = 0, r = n;
        while (l < r) { int m = (l + r) >> 1; if (batch[m] < g) l = m + 1; else r = m; }
        lo = l;
    }
    {
        int l = lo, r = n;
        while (l < r) { int m = (l + r) >> 1; if (batch[m] < g + 1) l = m + 1; else r = m; }
        hi = l;
    }
    int cntg = hi - lo;
    if (cntg <= 0) return;
    int per = (cntg + 3) >> 2;
    int s = lo + part * per, e = min(s + per, hi);
    int c2 = threadIdx.x & 63;
    int rl = threadIdx.x >> 6;
    float a0 = 0.f, a1 = 0.f;
    for (int i = s + rl; i < e; i += 4) {
        unsigned int u = ((const unsigned int*)(A + (size_t)i * HF))[c2];
        a0 += bf2f((unsigned short)(u & 0xFFFFu));
        a1 += bf2f((unsigned short)(u >> 16));
    }
    __shared__ float sh[512];
    sh[rl * 128 + c2 * 2] = a0;
    sh[rl * 128 + c2 * 2 + 1] = a1;
    __syncthreads();
    if (threadIdx.x < 128 && s < hi) {
        float s4 = sh[threadIdx.x] + sh[128 + threadIdx.x] + sh[256 + threadIdx.x] + sh[384 + threadIdx.x];
        atomicAdd(&gpool[g * HF + threadIdx.x], s4);
    }
}

// ---------------- fused bnsmall + fc (one block per graph row) ----------------
__global__ __launch_bounds__(128) void k_bnfc(const float* __restrict__ gpool,
                                              const float* __restrict__ g,
                                              const float* __restrict__ b,
                                              const float* __restrict__ Wfc,
                                              const float* __restrict__ bfc,
                                              float* __restrict__ G2) {
    int c = threadIdx.x, r = blockIdx.x;
    float s = 0.f, q = 0.f;
    for (int rr = 0; rr < GG; rr++) {
        float v = gpool[rr * HF + c];
        s += v; q += v * v;
    }
    float mean = s / GG;
    float var = q / GG - mean * mean;
    float sc = g[c] * rsqrtf(var + EPS), sh = b[c] - mean * sc;
    __shared__ float row[HF];
    row[c] = gpool[r * HF + c] * sc + sh;
    __syncthreads();
    float acc = bfc[c];
    for (int k = 0; k < HF; k++) acc += row[k] * Wfc[k * HF + c];
    G2[r * HF + c] = fmaxf(acc, 0.f);
}

__global__ void k_head2(const float* __restrict__ G2, const float* __restrict__ g,
                        const float* __restrict__ b, const float* __restrict__ Wcls,
                        const float* __restrict__ bcls, float* __restrict__ scratch,
                        float* __restrict__ outp) {
    __shared__ float Ls[GG * HF];
    int c = threadIdx.x;
    float s = 0.f, q = 0.f;
    for (int r = 0; r < GG; r++) { float v = G2[r * HF + c]; s += v; q += v * v; }
    float mean = s / GG;
    float var = q / GG - mean * mean;
    float sc = g[c] * rsqrtf(var + EPS), sh = b[c] - mean * sc;
    for (int r = 0; r < GG; r++) Ls[r * HF + c] = G2[r * HF + c] * sc + sh;
    __syncthreads();
    for (int o = c; o < GG * CC; o += HF) {
        int r = o / CC, j = o % CC;
        float acc = bcls[j];
        for (int k = 0; k < HF; k++) acc += Ls[r * HF + k] * Wcls[k * CC + j];
        scratch[o] = acc;
    }
    __threadfence_block();
    __syncthreads();
    int r = c;
    float m = -1e30f;
    for (int j = 0; j < CC; j++) m = fmaxf(m, scratch[r * CC + j]);
    float se = 0.f;
    for (int j = 0; j < CC; j++) se += expf(scratch[r * CC + j] - m);
    float ls = logf(se);
    for (int j = 0; j < CC; j++) outp[r * CC + j] = scratch[r * CC + j] - m - ls;
}

extern "C" void kernel_launch(void* const* d_in, const int* in_sizes, int n_in,
                              void* d_out, int out_size, void* d_ws, size_t ws_size,
                              hipStream_t stream) {
    const float* x         = (const float*)d_in[0];
    const int*   ei        = (const int*)d_in[1];
    const int*   batch     = (const int*)d_in[2];
    const float* bn_feat_g = (const float*)d_in[3];
    const float* bn_feat_b = (const float*)d_in[4];
    const float* W_feat    = (const float*)d_in[5];
    const float* conv_bn_g = (const float*)d_in[6];
    const float* conv_bn_b = (const float*)d_in[7];
    const float* conv_W    = (const float*)d_in[8];
    const float* conv_b    = (const float*)d_in[9];
    const float* bn_fc_g   = (const float*)d_in[10];
    const float* bn_fc_b   = (const float*)d_in[11];
    const float* W_fc      = (const float*)d_in[12];
    const float* b_fc      = (const float*)d_in[13];
    const float* bn_hid_g  = (const float*)d_in[14];
    const float* bn_hid_b  = (const float*)d_in[15];
    const float* W_cls     = (const float*)d_in[16];
    const float* b_cls     = (const float*)d_in[17];
    float* outp = (float*)d_out;

    int N = in_sizes[0] / HF;
    int E = in_sizes[1] / 2;

    char* w = (char*)d_ws;
    size_t off = 0;
    auto al = [&](size_t bytes) -> void* {
        off = (off + 255) & ~(size_t)255;
        void* p = w + off;
        off += bytes;
        return p;
    };
    unsigned short* A  = (unsigned short*)al((size_t)N * HF * 2);   // bf16 node features
    unsigned short* xb = (unsigned short*)al((size_t)N * HF * 2);   // bf16 copy of x
    unsigned char*  Bf = (unsigned char*)al((size_t)N * HF);        // int8 gather table
    float* rowscl = (float*)al((size_t)N * 4);
    int2*  epk    = (int2*)al((size_t)E * 8);
    int*   rank   = (int*)al((size_t)E * 4);
    float* dis    = (float*)al((size_t)N * 4);
    int*   offsb  = (int*)al((size_t)N * 4);
    unsigned short* Wtb = (unsigned short*)al(HF * HF * 2);
    float* biasT  = (float*)al(HF * 4);
    int*   bsum   = (int*)al(1024);
    int*   bscan  = (int*)al(1024);
    float* Gbn    = (float*)al(GG * HF * 4);
    float* G2     = (float*)al(GG * HF * 4);
    // zeroed region
    size_t z0 = (off + 255) & ~(size_t)255;
    off = z0;
    int*   cs    = (int*)al((size_t)N * 4);
    int*   cd    = (int*)al((size_t)N * 4);
    float* Sx    = (float*)al(2 * HF * 4);
    float* S0    = (float*)al(2 * HF * 4);
    float* S1    = (float*)al(2 * HF * 4);
    float* S2    = (float*)al(2 * HF * 4);
    float* gpool = (float*)al(GG * HF * 4);
    size_t zbytes = off - z0;
    hipMemsetAsync(w + z0, 0, zbytes, stream);

    int nbE = (E + 255) / 256;
    int nbN = (N + 255) / 256;
    int gemmGrid = (N + 127) / 128;

    // BN(x) stats + bf16 copy, then feat fold
    k_colstats<<<400, 256, 0, stream>>>(x, Sx, xb, N);
    k_foldbias<<<HF, HF, 0, stream>>>(Sx, 1.0f / N, bn_feat_g, bn_feat_b, W_feat, Wtb, biasT);

    // fused: feat GEMM (bf16 xb input) + edge degree count/rank atomics
    k_featfuse<<<gemmGrid + nbE, 256, 0, stream>>>(xb, Wtb, biasT, A, S0, N, gemmGrid,
                                                   ei, E, cs, cd, rank);

    // CSR offsets (two-level; scan3 eliminated — consumers add bscan inline)
    k_scan1<<<nbN, 256, 0, stream>>>(cd, cs, dis, offsb, bsum, N);
    k_scan2<<<1, 256, 0, stream>>>(bsum, bscan, nbN);

    float* Sarr[3] = {S0, S1, S2};
    for (int i = 0; i < 3; i++) {
        k_foldbias<<<HF, HF, 0, stream>>>(Sarr[i], 1.0f / N, conv_bn_g + i * HF, conv_bn_b + i * HF,
                                          conv_W + (size_t)i * HF * HF, Wtb, biasT);
        if (i == 0) {
            // layer-0 GEMM fused with CSR fill
            k_mgemm<0, 0, 1, 1><<<gemmGrid + nbE, 256, 0, stream>>>(
                A, Wtb, biasT, Bf, rowscl, N, nullptr, gemmGrid, ei, E, dis, offsb, bscan,
                rank, epk);
        } else {
            k_mgemm<0, 0, 1, 0><<<gemmGrid, 256, 0, stream>>>(
                A, Wtb, biasT, Bf, rowscl, N, nullptr, gemmGrid, nullptr, 0, nullptr, nullptr,
                nullptr, nullptr, nullptr);
        }
        if (i < 2)
            k_agg<1><<<(N + 31) / 32, 256, 0, stream>>>(Bf, rowscl, epk, offsb, bscan, cd, dis,
                                                        conv_b + i * HF, A, Sarr[i + 1], N);
        else
            k_agg<0><<<(N + 31) / 32, 256, 0, stream>>>(Bf, rowscl, epk, offsb, bscan, cd, dis,
                                                        conv_b + i * HF, A, nullptr, N);
    }

    // pool + head
    k_pool<<<GG * 4, 256, 0, stream>>>(A, batch, gpool, N);
    k_bnfc<<<GG, HF, 0, stream>>>(gpool, bn_fc_g, bn_fc_b, W_fc, b_fc, G2);
    k_head2<<<1, HF, 0, stream>>>(G2, bn_hid_g, bn_hid_b, W_cls, b_cls, Gbn, outp);
}

// Round 21
// 383.215 us; speedup vs baseline: 1.0928x; 1.0139x over previous
//
#include <hip/hip_runtime.h>
#include <hip/hip_bf16.h>

#define HF 128
#define GG 128
#define CC 10
#define EPS 1e-5f
#define TSTR 129          // padded LDS transpose stride (floats)
#define CAP 2048          // per-block cached CSR entries (16 KB)

typedef __attribute__((ext_vector_type(8))) short short8;
typedef __attribute__((ext_vector_type(4))) float f32x4;

__device__ inline unsigned short f2bf(float f) {
    unsigned int u = __float_as_uint(f);
    return (unsigned short)((u + 0x7FFFu + ((u >> 16) & 1u)) >> 16);
}

__device__ inline float bf2f(unsigned short h) {
    return __uint_as_float(((unsigned int)h) << 16);
}

// acc[0..7] += w * sext_int8x8(x,y)   (signed int8, exact decode)
__device__ inline void i8acc(float* acc, unsigned int x, unsigned int y, float w) {
    acc[0] = fmaf(w, (float)((int)(x << 24) >> 24), acc[0]);
    acc[1] = fmaf(w, (float)((int)(x << 16) >> 24), acc[1]);
    acc[2] = fmaf(w, (float)((int)(x << 8) >> 24), acc[2]);
    acc[3] = fmaf(w, (float)((int)x >> 24), acc[3]);
    acc[4] = fmaf(w, (float)((int)(y << 24) >> 24), acc[4]);
    acc[5] = fmaf(w, (float)((int)(y << 16) >> 24), acc[5]);
    acc[6] = fmaf(w, (float)((int)(y << 8) >> 24), acc[6]);
    acc[7] = fmaf(w, (float)((int)y >> 24), acc[7]);
}

__device__ inline void i8acc16(float* acc, uint4 u, float w) {
    i8acc(acc, u.x, u.y, w);
    i8acc(acc + 8, u.z, u.w, w);
}

__device__ inline unsigned int pk4i8(float a, float b, float c, float d, float inv) {
    int q0 = (int)rintf(a * inv), q1 = (int)rintf(b * inv);
    int q2 = (int)rintf(c * inv), q3 = (int)rintf(d * inv);
    return (unsigned int)(q0 & 255) | ((unsigned int)(q1 & 255) << 8) |
           ((unsigned int)(q2 & 255) << 16) | ((unsigned int)(q3 & 255) << 24);
}

// ---------------- BN stats over x (widened loads, no copy) ----------------
__global__ __launch_bounds__(256) void k_colstats(const float* __restrict__ X, float* stats,
                                                  int n) {
    int c4 = (threadIdx.x & 31) * 4;
    int rl = threadIdx.x >> 5;
    float s0 = 0.f, s1 = 0.f, s2 = 0.f, s3 = 0.f;
    float q0 = 0.f, q1 = 0.f, q2 = 0.f, q3 = 0.f;
    for (int i = blockIdx.x * 8 + rl; i < n; i += gridDim.x * 8) {
        float4 v = *(const float4*)(X + (size_t)i * HF + c4);
        s0 += v.x; q0 += v.x * v.x;
        s1 += v.y; q1 += v.y * v.y;
        s2 += v.z; q2 += v.z * v.z;
        s3 += v.w; q3 += v.w * v.w;
    }
    __shared__ float sh[2048];
    sh[rl * 128 + c4 + 0] = s0; sh[rl * 128 + c4 + 1] = s1;
    sh[rl * 128 + c4 + 2] = s2; sh[rl * 128 + c4 + 3] = s3;
    sh[1024 + rl * 128 + c4 + 0] = q0; sh[1024 + rl * 128 + c4 + 1] = q1;
    sh[1024 + rl * 128 + c4 + 2] = q2; sh[1024 + rl * 128 + c4 + 3] = q3;
    __syncthreads();
    if (threadIdx.x < 128) {
        float ts = 0.f, tq = 0.f;
        for (int g = 0; g < 8; g++) {
            ts += sh[g * 128 + threadIdx.x];
            tq += sh[1024 + g * 128 + threadIdx.x];
        }
        atomicAdd(&stats[threadIdx.x], ts);
        atomicAdd(&stats[HF + threadIdx.x], tq);
    }
}

// ------- BN fold -------
__global__ void k_foldbias(const float* __restrict__ stats, float cntInv,
                           const float* __restrict__ g, const float* __restrict__ b,
                           const float* __restrict__ W, unsigned short* __restrict__ Wtb,
                           float* __restrict__ biasT) {
    int n = blockIdx.x, k = threadIdx.x;
    float mean = stats[k] * cntInv;
    float var = stats[HF + k] * cntInv - mean * mean;
    float sc = g[k] * rsqrtf(var + EPS);
    float shf = b[k] - mean * sc;
    float wkn = W[k * HF + n];
    Wtb[n * HF + k] = f2bf(sc * wkn);
    __shared__ float red[128];
    red[k] = shf * wkn;
    __syncthreads();
    for (int o = 64; o > 0; o >>= 1) {
        if (k < o) red[k] += red[k + o];
        __syncthreads();
    }
    if (k == 0) biasT[n] = red[0];
}

// ---- fused: feat-layer MFMA GEMM on fp32 x (blocks [0,gB)) + edge count/rank atomics ----
// fp32-input body (VGPR ~80) keeps kernel-wide register footprint low so the
// co-resident atomic blocks retain concurrency (measured: 100 µs vs 105-110 for bf16 input).
__global__ __launch_bounds__(256) void k_featfuse(const float* __restrict__ Ain,
                                                  const unsigned short* __restrict__ Wtb,
                                                  const float* __restrict__ biasT,
                                                  unsigned short* __restrict__ outv,
                                                  float* __restrict__ stats, int n, int gB,
                                                  const int* __restrict__ ei, int E,
                                                  int* cs, int* cd, int* __restrict__ rank) {
    __shared__ float Ls[4][16 * TSTR];
    __shared__ float bsh[128];
    if ((int)blockIdx.x >= gB) {
        int e = ((int)blockIdx.x - gB) * 256 + threadIdx.x;
        if (e < E) {
            atomicAdd(&cs[ei[e]], 1);
            rank[e] = atomicAdd(&cd[ei[E + e]], 1);
        }
        return;
    }
    int l = threadIdx.x & 63, w = threadIdx.x >> 6;
    int lr = l & 15, lc = l >> 4;
    int rowbase = blockIdx.x * 128 + w * 32;
    if (threadIdx.x < 128) bsh[threadIdx.x] = biasT[threadIdx.x];

    f32x4 acc[2][8];
#pragma unroll
    for (int rt = 0; rt < 2; rt++)
#pragma unroll
        for (int nt = 0; nt < 8; nt++) acc[rt][nt] = (f32x4){0.f, 0.f, 0.f, 0.f};

    union U { uint4 u; short8 s; };

    for (int ks = 0; ks < 4; ks++) {
        short8 af[2];
#pragma unroll
        for (int rt = 0; rt < 2; rt++) {
            int row = rowbase + rt * 16 + lr;
            if (row < n) {
                const float4* xp = (const float4*)(Ain + (size_t)row * HF + ks * 32 + lc * 8);
                float4 v0 = xp[0], v1 = xp[1];
                short8 a;
                a[0] = (short)f2bf(v0.x); a[1] = (short)f2bf(v0.y);
                a[2] = (short)f2bf(v0.z); a[3] = (short)f2bf(v0.w);
                a[4] = (short)f2bf(v1.x); a[5] = (short)f2bf(v1.y);
                a[6] = (short)f2bf(v1.z); a[7] = (short)f2bf(v1.w);
                af[rt] = a;
            } else af[rt] = (short8){0,0,0,0,0,0,0,0};
        }
#pragma unroll
        for (int nt = 0; nt < 8; nt++) {
            U ub;
            ub.u = *(const uint4*)(Wtb + (size_t)(nt * 16 + lr) * HF + ks * 32 + lc * 8);
            acc[0][nt] = __builtin_amdgcn_mfma_f32_16x16x32_bf16(af[0], ub.s, acc[0][nt], 0, 0, 0);
            acc[1][nt] = __builtin_amdgcn_mfma_f32_16x16x32_bf16(af[1], ub.s, acc[1][nt], 0, 0, 0);
        }
    }
    __syncthreads();   // bsh ready

    {   // fused column stats (post bias+relu)
        float s[8], q[8];
#pragma unroll
        for (int nt = 0; nt < 8; nt++) { s[nt] = 0.f; q[nt] = 0.f; }
#pragma unroll
        for (int rt = 0; rt < 2; rt++) {
#pragma unroll
            for (int nt = 0; nt < 8; nt++) {
                float bias = bsh[nt * 16 + lr];
#pragma unroll
                for (int r = 0; r < 4; r++) {
                    int row = rowbase + rt * 16 + lc * 4 + r;
                    if (row < n) {
                        float v = fmaxf(acc[rt][nt][r] + bias, 0.f);
                        s[nt] += v; q[nt] += v * v;
                    }
                }
            }
        }
#pragma unroll
        for (int nt = 0; nt < 8; nt++) {
            s[nt] += __shfl_xor(s[nt], 16);
            q[nt] += __shfl_xor(q[nt], 16);
            s[nt] += __shfl_xor(s[nt], 32);
            q[nt] += __shfl_xor(q[nt], 32);
        }
        if (lc == 0) {
#pragma unroll
            for (int nt = 0; nt < 8; nt++) {
                atomicAdd(&stats[nt * 16 + lr], s[nt]);
                atomicAdd(&stats[HF + nt * 16 + lr], q[nt]);
            }
        }
    }

    // transpose via LDS (padded stride), coalesced bf16 stores
    float* LsW = Ls[w];
    for (int rt = 0; rt < 2; rt++) {
#pragma unroll
        for (int nt = 0; nt < 8; nt++)
#pragma unroll
            for (int r = 0; r < 4; r++)
                LsW[(lc * 4 + r) * TSTR + nt * 16 + lr] = acc[rt][nt][r];
        __syncthreads();
        int r16 = l >> 2, cc = (l & 3) * 32;
        int row = rowbase + rt * 16 + r16;
        if (row < n) {
            unsigned int o[16];
#pragma unroll
            for (int j = 0; j < 16; j++) {
                float v0 = fmaxf(LsW[r16 * TSTR + cc + 2 * j] + bsh[cc + 2 * j], 0.f);
                float v1 = fmaxf(LsW[r16 * TSTR + cc + 2 * j + 1] + bsh[cc + 2 * j + 1], 0.f);
                o[j] = (unsigned int)f2bf(v0) | ((unsigned int)f2bf(v1) << 16);
            }
            uint4* dst = (uint4*)(outv + (size_t)row * HF + cc);
            dst[0] = make_uint4(o[0], o[1], o[2], o[3]);
            dst[1] = make_uint4(o[4], o[5], o[6], o[7]);
            dst[2] = make_uint4(o[8], o[9], o[10], o[11]);
            dst[3] = make_uint4(o[12], o[13], o[14], o[15]);
        }
        __syncthreads();
    }
}

__global__ void k_scan1(const int* __restrict__ cd, const int* __restrict__ cs,
                        float* __restrict__ dis, int* offs, int* bsum, int n) {
    __shared__ int sh[256];
    int t = threadIdx.x, i = blockIdx.x * 256 + t;
    if (i < n) dis[i] = rsqrtf((float)(1 + cs[i]));
    int v = (i < n) ? cd[i] : 0;
    sh[t] = v; __syncthreads();
    for (int o = 1; o < 256; o <<= 1) {
        int x = (t >= o) ? sh[t - o] : 0;
        __syncthreads();
        sh[t] += x;
        __syncthreads();
    }
    if (i < n) offs[i] = sh[t] - v;   // exclusive within block
    if (t == 255) bsum[blockIdx.x] = sh[255];
}

__global__ void k_scan2(const int* __restrict__ bsum, int* bscan, int nb) {
    __shared__ int sh[256];
    int t = threadIdx.x;
    int v = (t < nb) ? bsum[t] : 0;
    sh[t] = v; __syncthreads();
    for (int o = 1; o < 256; o <<= 1) {
        int x = (t >= o) ? sh[t - o] : 0;
        __syncthreads();
        sh[t] += x;
        __syncthreads();
    }
    if (t < nb) bscan[t] = sh[t] - v;
}

// ---------------- MFMA GEMM (conv layers) + optional fused CSR fill ----------------
// Fill computes offs inline: offsb[d] + bscan[d>>8] + rank[e]  (no scan3 pass).
template <int RELU, int STATS, int OUTQ, int FILL>
__global__ __launch_bounds__(256) void k_mgemm(const unsigned short* __restrict__ Ain,
                                               const unsigned short* __restrict__ Wtb,
                                               const float* __restrict__ biasT,
                                               void* __restrict__ outv,
                                               float* __restrict__ rowscl,
                                               int n, float* stats, int gB,
                                               const int* __restrict__ ei, int E,
                                               const float* __restrict__ dis,
                                               const int* __restrict__ offsb,
                                               const int* __restrict__ bscan,
                                               const int* __restrict__ rank,
                                               int2* __restrict__ epk) {
    __shared__ float Ls[4][16 * TSTR];
    __shared__ float bsh[128];
    if (FILL) {
        if ((int)blockIdx.x >= gB) {
            int e = ((int)blockIdx.x - gB) * 256 + threadIdx.x;
            if (e < E) {
                int s = ei[e], d = ei[E + e];
                epk[offsb[d] + bscan[d >> 8] + rank[e]] =
                    make_int2(s, __float_as_int(dis[s] * dis[d]));
            }
            return;
        }
    }
    int l = threadIdx.x & 63, w = threadIdx.x >> 6;
    int lr = l & 15, lc = l >> 4;
    int rowbase = blockIdx.x * 128 + w * 32;
    if (threadIdx.x < 128) bsh[threadIdx.x] = biasT[threadIdx.x];

    f32x4 acc[2][8];
#pragma unroll
    for (int rt = 0; rt < 2; rt++)
#pragma unroll
        for (int nt = 0; nt < 8; nt++) acc[rt][nt] = (f32x4){0.f, 0.f, 0.f, 0.f};

    union U { uint4 u; short8 s; };

    for (int ks = 0; ks < 4; ks++) {
        short8 af[2];
#pragma unroll
        for (int rt = 0; rt < 2; rt++) {
            int row = rowbase + rt * 16 + lr;
            if (row < n) {
                U u;
                u.u = *(const uint4*)(Ain + (size_t)row * HF + ks * 32 + lc * 8);
                af[rt] = u.s;
            } else af[rt] = (short8){0,0,0,0,0,0,0,0};
        }
#pragma unroll
        for (int nt = 0; nt < 8; nt++) {
            U ub;
            ub.u = *(const uint4*)(Wtb + (size_t)(nt * 16 + lr) * HF + ks * 32 + lc * 8);
            acc[0][nt] = __builtin_amdgcn_mfma_f32_16x16x32_bf16(af[0], ub.s, acc[0][nt], 0, 0, 0);
            acc[1][nt] = __builtin_amdgcn_mfma_f32_16x16x32_bf16(af[1], ub.s, acc[1][nt], 0, 0, 0);
        }
    }
    __syncthreads();

    if (STATS) {
        float s[8], q[8];
#pragma unroll
        for (int nt = 0; nt < 8; nt++) { s[nt] = 0.f; q[nt] = 0.f; }
#pragma unroll
        for (int rt = 0; rt < 2; rt++) {
#pragma unroll
            for (int nt = 0; nt < 8; nt++) {
                float bias = bsh[nt * 16 + lr];
#pragma unroll
                for (int r = 0; r < 4; r++) {
                    int row = rowbase + rt * 16 + lc * 4 + r;
                    if (row < n) {
                        float v = acc[rt][nt][r] + bias;
                        if (RELU) v = fmaxf(v, 0.f);
                        s[nt] += v; q[nt] += v * v;
                    }
                }
            }
        }
#pragma unroll
        for (int nt = 0; nt < 8; nt++) {
            s[nt] += __shfl_xor(s[nt], 16);
            q[nt] += __shfl_xor(q[nt], 16);
            s[nt] += __shfl_xor(s[nt], 32);
            q[nt] += __shfl_xor(q[nt], 32);
        }
        if (lc == 0) {
#pragma unroll
            for (int nt = 0; nt < 8; nt++) {
                atomicAdd(&stats[nt * 16 + lr], s[nt]);
                atomicAdd(&stats[HF + nt * 16 + lr], q[nt]);
            }
        }
    }

    float* LsW = Ls[w];
    for (int rt = 0; rt < 2; rt++) {
#pragma unroll
        for (int nt = 0; nt < 8; nt++)
#pragma unroll
            for (int r = 0; r < 4; r++)
                LsW[(lc * 4 + r) * TSTR + nt * 16 + lr] = acc[rt][nt][r];
        __syncthreads();
        int r16 = l >> 2, cc = (l & 3) * 32;
        int row = rowbase + rt * 16 + r16;
        if (row < n) {
            float v[32];
#pragma unroll
            for (int j = 0; j < 32; j++) {
                float tv = LsW[r16 * TSTR + cc + j] + bsh[cc + j];
                if (RELU) tv = fmaxf(tv, 0.f);
                v[j] = tv;
            }
            if (OUTQ) {
                float m = 0.f;
#pragma unroll
                for (int j = 0; j < 32; j++) m = fmaxf(m, fabsf(v[j]));
                m = fmaxf(m, __shfl_xor(m, 1));
                m = fmaxf(m, __shfl_xor(m, 2));
                float inv = (m > 1e-20f) ? 127.f / m : 0.f;
                unsigned int o[8];
#pragma unroll
                for (int j = 0; j < 8; j++)
                    o[j] = pk4i8(v[4 * j], v[4 * j + 1], v[4 * j + 2], v[4 * j + 3], inv);
                uint4* dst = (uint4*)((unsigned char*)outv + (size_t)row * 128 + cc);
                dst[0] = make_uint4(o[0], o[1], o[2], o[3]);
                dst[1] = make_uint4(o[4], o[5], o[6], o[7]);
                if ((l & 3) == 0) rowscl[row] = m * (1.f / 127.f);
            } else {
                unsigned int o[16];
#pragma unroll
                for (int j = 0; j < 16; j++)
                    o[j] = (unsigned int)f2bf(v[2 * j]) | ((unsigned int)f2bf(v[2 * j + 1]) << 16);
                uint4* dst = (uint4*)((unsigned short*)outv + (size_t)row * HF + cc);
                dst[0] = make_uint4(o[0], o[1], o[2], o[3]);
                dst[1] = make_uint4(o[4], o[5], o[6], o[7]);
                dst[2] = make_uint4(o[8], o[9], o[10], o[11]);
                dst[3] = make_uint4(o[12], o[13], o[14], o[15]);
            }
        }
        __syncthreads();
    }
}

// ------- aggregation: LDS-staged CSR (premultiplied weights), offs computed inline -------
template <int STATS>
__global__ __launch_bounds__(256) void k_agg(const unsigned char* __restrict__ B,
                                             const float* __restrict__ rsc,
                                             const int2* __restrict__ epk,
                                             const int* __restrict__ offsb,
                                             const int* __restrict__ bscan,
                                             const int* __restrict__ cnt,
                                             const float* __restrict__ dis,
                                             const float* __restrict__ convb,
                                             unsigned short* __restrict__ out,
                                             float* stats, int n) {
    __shared__ int2 cache[CAP];   // 16 KB; reused as float[4096] for stats
    int t = threadIdx.x;
    int lg = t & 7;
    int nb0 = blockIdx.x * 32;
    int node = nb0 + (t >> 3);
    int endNode = min(nb0 + 32, n);
    int segBase = (nb0 < n) ? (offsb[nb0] + bscan[nb0 >> 8]) : 0;
    int segEnd = (endNode > nb0)
                     ? (offsb[endNode - 1] + bscan[(endNode - 1) >> 8] + cnt[endNode - 1])
                     : segBase;

    for (int idx = segBase + t; idx < segEnd; idx += 256) {
        int li = idx - segBase;
        if (li >= CAP) break;
        int2 p = epk[idx];
        cache[li] = make_int2(p.x, __float_as_int(__int_as_float(p.y) * rsc[p.x]));
    }
    __syncthreads();

    const uint4* Bv = (const uint4*)B;
    float acc[16];
#pragma unroll
    for (int k = 0; k < 16; k++) acc[k] = 0.f;
    float v[16];
    if (node < n) {
        float d = dis[node];
        i8acc16(acc, Bv[(size_t)node * 8 + lg], d * d * rsc[node]);
        int j0 = offsb[node] + bscan[node >> 8], e0 = j0 + cnt[node];
        if (e0 - segBase <= CAP) {
            int li = j0 - segBase, le = e0 - segBase;
            int2 p[8];
#pragma unroll
            for (int u = 0; u < 8; u++) p[u] = (li + u < le) ? cache[li + u] : make_int2(node, 0);
            while (li < le) {
                uint4 g0 = Bv[(size_t)p[0].x * 8 + lg];
                uint4 g1 = Bv[(size_t)p[1].x * 8 + lg];
                uint4 g2 = Bv[(size_t)p[2].x * 8 + lg];
                uint4 g3 = Bv[(size_t)p[3].x * 8 + lg];
                uint4 g4 = Bv[(size_t)p[4].x * 8 + lg];
                uint4 g5 = Bv[(size_t)p[5].x * 8 + lg];
                uint4 g6 = Bv[(size_t)p[6].x * 8 + lg];
                uint4 g7 = Bv[(size_t)p[7].x * 8 + lg];
                int ln = li + 8;
                int2 pn[8];
#pragma unroll
                for (int u = 0; u < 8; u++) pn[u] = (ln + u < le) ? cache[ln + u] : make_int2(node, 0);
                i8acc16(acc, g0, __int_as_float(p[0].y));
                i8acc16(acc, g1, __int_as_float(p[1].y));
                i8acc16(acc, g2, __int_as_float(p[2].y));
                i8acc16(acc, g3, __int_as_float(p[3].y));
                i8acc16(acc, g4, __int_as_float(p[4].y));
                i8acc16(acc, g5, __int_as_float(p[5].y));
                i8acc16(acc, g6, __int_as_float(p[6].y));
                i8acc16(acc, g7, __int_as_float(p[7].y));
#pragma unroll
                for (int u = 0; u < 8; u++) p[u] = pn[u];
                li = ln;
            }
        } else {
            for (int j = j0; j < e0; j++) {
                int2 p = epk[j];
                float wq = __int_as_float(p.y) * rsc[p.x];
                i8acc16(acc, Bv[(size_t)p.x * 8 + lg], wq);
            }
        }
        const float4* cb = (const float4*)convb;
        float4 b0 = cb[lg * 4], b1 = cb[lg * 4 + 1], b2 = cb[lg * 4 + 2], b3 = cb[lg * 4 + 3];
        v[0]  = fmaxf(acc[0]  + b0.x, 0.f); v[1]  = fmaxf(acc[1]  + b0.y, 0.f);
        v[2]  = fmaxf(acc[2]  + b0.z, 0.f); v[3]  = fmaxf(acc[3]  + b0.w, 0.f);
        v[4]  = fmaxf(acc[4]  + b1.x, 0.f); v[5]  = fmaxf(acc[5]  + b1.y, 0.f);
        v[6]  = fmaxf(acc[6]  + b1.z, 0.f); v[7]  = fmaxf(acc[7]  + b1.w, 0.f);
        v[8]  = fmaxf(acc[8]  + b2.x, 0.f); v[9]  = fmaxf(acc[9]  + b2.y, 0.f);
        v[10] = fmaxf(acc[10] + b2.z, 0.f); v[11] = fmaxf(acc[11] + b2.w, 0.f);
        v[12] = fmaxf(acc[12] + b3.x, 0.f); v[13] = fmaxf(acc[13] + b3.y, 0.f);
        v[14] = fmaxf(acc[14] + b3.z, 0.f); v[15] = fmaxf(acc[15] + b3.w, 0.f);
        uint4 o0, o1;
        o0.x = (unsigned int)f2bf(v[0])  | ((unsigned int)f2bf(v[1])  << 16);
        o0.y = (unsigned int)f2bf(v[2])  | ((unsigned int)f2bf(v[3])  << 16);
        o0.z = (unsigned int)f2bf(v[4])  | ((unsigned int)f2bf(v[5])  << 16);
        o0.w = (unsigned int)f2bf(v[6])  | ((unsigned int)f2bf(v[7])  << 16);
        o1.x = (unsigned int)f2bf(v[8])  | ((unsigned int)f2bf(v[9])  << 16);
        o1.y = (unsigned int)f2bf(v[10]) | ((unsigned int)f2bf(v[11]) << 16);
        o1.z = (unsigned int)f2bf(v[12]) | ((unsigned int)f2bf(v[13]) << 16);
        o1.w = (unsigned int)f2bf(v[14]) | ((unsigned int)f2bf(v[15]) << 16);
        uint4* op = (uint4*)out + (size_t)node * 16 + lg * 2;
        op[0] = o0; op[1] = o1;
    } else {
#pragma unroll
        for (int k = 0; k < 16; k++) v[k] = 0.f;
    }
    if (STATS) {
        __syncthreads();
        float* sh = (float*)cache;
        int nb = t >> 3;
#pragma unroll
        for (int k = 0; k < 16; k++) sh[nb * 128 + lg * 16 + k] = v[k];
        __syncthreads();
        if (t < 128) {
            float ts = 0.f, tq = 0.f;
            for (int g = 0; g < 32; g++) {
                float val = sh[g * 128 + t];
                ts += val; tq += val * val;
            }
            atomicAdd(&stats[t], ts);
            atomicAdd(&stats[HF + t], tq);
        }
    }
}

// ---------------- global add pool ----------------
__global__ __launch_bounds__(256) void k_pool(const unsigned short* __restrict__ A,
                                              const int* __restrict__ batch,
                                              float* gpool, int n) {
    int g = blockIdx.x >> 2, part = blockIdx.x & 3;
    int lo, hi;
    {
        int l = 0, r = n;
        while (l < r) { int m = (l + r) >> 1; if (batch[m] < g) l = m + 1; else r = m; }
        lo = l;
    }
    {
        int l = lo, r = n;
        while (l < r) { int m = (l + r) >> 1; if (batch[m] < g + 1) l = m + 1; else r = m; }
        hi = l;
    }
    int cntg = hi - lo;
    if (cntg <= 0) return;
    int per = (cntg + 3) >> 2;
    int s = lo + part * per, e = min(s + per, hi);
    int c2 = threadIdx.x & 63;
    int rl = threadIdx.x >> 6;
    float a0 = 0.f, a1 = 0.f;
    for (int i = s + rl; i < e; i += 4) {
        unsigned int u = ((const unsigned int*)(A + (size_t)i * HF))[c2];
        a0 += bf2f((unsigned short)(u & 0xFFFFu));
        a1 += bf2f((unsigned short)(u >> 16));
    }
    __shared__ float sh[512];
    sh[rl * 128 + c2 * 2] = a0;
    sh[rl * 128 + c2 * 2 + 1] = a1;
    __syncthreads();
    if (threadIdx.x < 128 && s < hi) {
        float s4 = sh[threadIdx.x] + sh[128 + threadIdx.x] + sh[256 + threadIdx.x] + sh[384 + threadIdx.x];
        atomicAdd(&gpool[g * HF + threadIdx.x], s4);
    }
}

// ---------------- fused bnsmall + fc (one block per graph row) ----------------
__global__ __launch_bounds__(128) void k_bnfc(const float* __restrict__ gpool,
                                              const float* __restrict__ g,
                                              const float* __restrict__ b,
                                              const float* __restrict__ Wfc,
                                              const float* __restrict__ bfc,
                                              float* __restrict__ G2) {
    int c = threadIdx.x, r = blockIdx.x;
    float s = 0.f, q = 0.f;
    for (int rr = 0; rr < GG; rr++) {
        float v = gpool[rr * HF + c];
        s += v; q += v * v;
    }
    float mean = s / GG;
    float var = q / GG - mean * mean;
    float sc = g[c] * rsqrtf(var + EPS), sh = b[c] - mean * sc;
    __shared__ float row[HF];
    row[c] = gpool[r * HF + c] * sc + sh;
    __syncthreads();
    float acc = bfc[c];
    for (int k = 0; k < HF; k++) acc += row[k] * Wfc[k * HF + c];
    G2[r * HF + c] = fmaxf(acc, 0.f);
}

__global__ void k_head2(const float* __restrict__ G2, const float* __restrict__ g,
                        const float* __restrict__ b, const float* __restrict__ Wcls,
                        const float* __restrict__ bcls, float* __restrict__ scratch,
                        float* __restrict__ outp) {
    __shared__ float Ls[GG * HF];
    int c = threadIdx.x;
    float s = 0.f, q = 0.f;
    for (int r = 0; r < GG; r++) { float v = G2[r * HF + c]; s += v; q += v * v; }
    float mean = s / GG;
    float var = q / GG - mean * mean;
    float sc = g[c] * rsqrtf(var + EPS), sh = b[c] - mean * sc;
    for (int r = 0; r < GG; r++) Ls[r * HF + c] = G2[r * HF + c] * sc + sh;
    __syncthreads();
    for (int o = c; o < GG * CC; o += HF) {
        int r = o / CC, j = o % CC;
        float acc = bcls[j];
        for (int k = 0; k < HF; k++) acc += Ls[r * HF + k] * Wcls[k * CC + j];
        scratch[o] = acc;
    }
    __threadfence_block();
    __syncthreads();
    int r = c;
    float m = -1e30f;
    for (int j = 0; j < CC; j++) m = fmaxf(m, scratch[r * CC + j]);
    float se = 0.f;
    for (int j = 0; j < CC; j++) se += expf(scratch[r * CC + j] - m);
    float ls = logf(se);
    for (int j = 0; j < CC; j++) outp[r * CC + j] = scratch[r * CC + j] - m - ls;
}

extern "C" void kernel_launch(void* const* d_in, const int* in_sizes, int n_in,
                              void* d_out, int out_size, void* d_ws, size_t ws_size,
                              hipStream_t stream) {
    const float* x         = (const float*)d_in[0];
    const int*   ei        = (const int*)d_in[1];
    const int*   batch     = (const int*)d_in[2];
    const float* bn_feat_g = (const float*)d_in[3];
    const float* bn_feat_b = (const float*)d_in[4];
    const float* W_feat    = (const float*)d_in[5];
    const float* conv_bn_g = (const float*)d_in[6];
    const float* conv_bn_b = (const float*)d_in[7];
    const float* conv_W    = (const float*)d_in[8];
    const float* conv_b    = (const float*)d_in[9];
    const float* bn_fc_g   = (const float*)d_in[10];
    const float* bn_fc_b   = (const float*)d_in[11];
    const float* W_fc      = (const float*)d_in[12];
    const float* b_fc      = (const float*)d_in[13];
    const float* bn_hid_g  = (const float*)d_in[14];
    const float* bn_hid_b  = (const float*)d_in[15];
    const float* W_cls     = (const float*)d_in[16];
    const float* b_cls     = (const float*)d_in[17];
    float* outp = (float*)d_out;

    int N = in_sizes[0] / HF;
    int E = in_sizes[1] / 2;

    char* w = (char*)d_ws;
    size_t off = 0;
    auto al = [&](size_t bytes) -> void* {
        off = (off + 255) & ~(size_t)255;
        void* p = w + off;
        off += bytes;
        return p;
    };
    unsigned short* A  = (unsigned short*)al((size_t)N * HF * 2);   // bf16 node features
    unsigned char*  Bf = (unsigned char*)al((size_t)N * HF);        // int8 gather table
    float* rowscl = (float*)al((size_t)N * 4);
    int2*  epk    = (int2*)al((size_t)E * 8);
    int*   rank   = (int*)al((size_t)E * 4);
    float* dis    = (float*)al((size_t)N * 4);
    int*   offsb  = (int*)al((size_t)N * 4);
    unsigned short* Wtb = (unsigned short*)al(HF * HF * 2);
    float* biasT  = (float*)al(HF * 4);
    int*   bsum   = (int*)al(1024);
    int*   bscan  = (int*)al(1024);
    float* Gbn    = (float*)al(GG * HF * 4);
    float* G2     = (float*)al(GG * HF * 4);
    // zeroed region
    size_t z0 = (off + 255) & ~(size_t)255;
    off = z0;
    int*   cs    = (int*)al((size_t)N * 4);
    int*   cd    = (int*)al((size_t)N * 4);
    float* Sx    = (float*)al(2 * HF * 4);
    float* S0    = (float*)al(2 * HF * 4);
    float* S1    = (float*)al(2 * HF * 4);
    float* S2    = (float*)al(2 * HF * 4);
    float* gpool = (float*)al(GG * HF * 4);
    size_t zbytes = off - z0;
    hipMemsetAsync(w + z0, 0, zbytes, stream);

    int nbE = (E + 255) / 256;
    int nbN = (N + 255) / 256;
    int gemmGrid = (N + 127) / 128;

    // BN(x) stats, then feat fold
    k_colstats<<<400, 256, 0, stream>>>(x, Sx, N);
    k_foldbias<<<HF, HF, 0, stream>>>(Sx, 1.0f / N, bn_feat_g, bn_feat_b, W_feat, Wtb, biasT);

    // fused: feat GEMM (fp32 x input, low-VGPR) + edge degree count/rank atomics
    k_featfuse<<<gemmGrid + nbE, 256, 0, stream>>>(x, Wtb, biasT, A, S0, N, gemmGrid,
                                                   ei, E, cs, cd, rank);

    // CSR offsets (two-level; scan3 eliminated — consumers add bscan inline)
    k_scan1<<<nbN, 256, 0, stream>>>(cd, cs, dis, offsb, bsum, N);
    k_scan2<<<1, 256, 0, stream>>>(bsum, bscan, nbN);

    float* Sarr[3] = {S0, S1, S2};
    for (int i = 0; i < 3; i++) {
        k_foldbias<<<HF, HF, 0, stream>>>(Sarr[i], 1.0f / N, conv_bn_g + i * HF, conv_bn_b + i * HF,
                                          conv_W + (size_t)i * HF * HF, Wtb, biasT);
        if (i == 0) {
            // layer-0 GEMM fused with CSR fill
            k_mgemm<0, 0, 1, 1><<<gemmGrid + nbE, 256, 0, stream>>>(
                A, Wtb, biasT, Bf, rowscl, N, nullptr, gemmGrid, ei, E, dis, offsb, bscan,
                rank, epk);
        } else {
            k_mgemm<0, 0, 1, 0><<<gemmGrid, 256, 0, stream>>>(
                A, Wtb, biasT, Bf, rowscl, N, nullptr, gemmGrid, nullptr, 0, nullptr, nullptr,
                nullptr, nullptr, nullptr);
        }
        if (i < 2)
            k_agg<1><<<(N + 31) / 32, 256, 0, stream>>>(Bf, rowscl, epk, offsb, bscan, cd, dis,
                                                        conv_b + i * HF, A, Sarr[i + 1], N);
        else
            k_agg<0><<<(N + 31) / 32, 256, 0, stream>>>(Bf, rowscl, epk, offsb, bscan, cd, dis,
                                                        conv_b + i * HF, A, nullptr, N);
    }

    // pool + head
    k_pool<<<GG * 4, 256, 0, stream>>>(A, batch, gpool, N);
    k_bnfc<<<GG, HF, 0, stream>>>(gpool, bn_fc_g, bn_fc_b, W_fc, b_fc, G2);
    k_head2<<<1, HF, 0, stream>>>(G2, bn_hid_g, bn_hid_b, W_cls, b_cls, Gbn, outp);
}